// Round 2
// baseline (368.573 us; speedup 1.0000x reference)
//
#include <hip/hip_runtime.h>
#include <math.h>

#define HW    16384
#define WID   128
#define NB    4
// output section offsets (floats)
#define OFF_U 3932160
#define OFF_L 4259840
#define OFF_F 4456448

__device__ __forceinline__ float sig_(float x)  { return 1.f/(1.f+__expf(-x)); }
__device__ __forceinline__ float tanh_(float x) { float e=__expf(2.f*x); return 1.f - 2.f/(e+1.f); }

// ---------------------------------------------------------------------------
// Kernel A: decomp maps + softmax atts, Fdep attention, decomposition messages
// grid 256 x 256 threads, one thread per pixel (b,y,x)
// ---------------------------------------------------------------------------
__global__ __launch_bounds__(256)
void k_att_dec(const float* __restrict__ hn, const float* __restrict__ pnn,
               const float* __restrict__ Wdau, const float* __restrict__ bdau,
               const float* __restrict__ Wdal, const float* __restrict__ bdal,
               const float* __restrict__ Wd1, const float* __restrict__ s1v, const float* __restrict__ t1v,
               const float* __restrict__ Wd2, const float* __restrict__ s2v, const float* __restrict__ t2v,
               const float* __restrict__ Wa0, const float* __restrict__ Wa1, const float* __restrict__ Wa2,
               const float* __restrict__ Wa3, const float* __restrict__ Wa4, const float* __restrict__ Wa5,
               const float* __restrict__ batt,
               float* __restrict__ out, float* __restrict__ wmsg)
{
  const int g   = blockIdx.x*256 + threadIdx.x;
  const int b   = g >> 14;
  const int pix = g & 16383;

  float h0[10], h1[10];
#pragma unroll
  for (int c=0;c<10;c++){
    h0[c] = hn[(b*10+c)*HW + pix];
    h1[c] = hn[((NB+b)*10+c)*HW + pix];
  }

  // ---- decomposition attention maps + softmax (upper: 5ch, lower: 3ch) ----
  float au[5], al[3];
  {
    float v[5]; float mx = -1e30f;
#pragma unroll
    for (int o=0;o<5;o++){
      float a = bdau[o];
#pragma unroll
      for (int c=0;c<10;c++) a += Wdau[o*10+c]*h0[c];
      out[OFF_U + (b*5+o)*HW + pix] = a;
      v[o]=a; mx = fmaxf(mx,a);
    }
    float s=0.f;
#pragma unroll
    for (int o=0;o<5;o++){ v[o]=__expf(v[o]-mx); s+=v[o]; }
    float rs = 1.f/s;
#pragma unroll
    for (int o=0;o<5;o++) au[o]=v[o]*rs;
  }
  {
    float v[3]; float mx = -1e30f;
#pragma unroll
    for (int o=0;o<3;o++){
      float a = bdal[o];
#pragma unroll
      for (int c=0;c<10;c++) a += Wdal[o*10+c]*h1[c];
      out[OFF_L + (b*3+o)*HW + pix] = a;
      v[o]=a; mx = fmaxf(mx,a);
    }
    float s=0.f;
#pragma unroll
    for (int o=0;o<3;o++){ v[o]=__expf(v[o]-mx); s+=v[o]; }
    float rs = 1.f/s;
#pragma unroll
    for (int o=0;o<3;o++) al[o]=v[o]*rs;
  }

  // ---- Fdep attention per node (PART_LIST_LIST = [[1],[0,2,3,4],[1],[1],[1,5],[4]]) ----
  {
    float a0=batt[0], a1=batt[1], a2=batt[2], a3=batt[3], a4=batt[4], a5=batt[5];
#pragma unroll
    for (int c=0;c<10;c++){
      float p0 = pnn[((0*NB+b)*10+c)*HW+pix];
      float p1 = pnn[((1*NB+b)*10+c)*HW+pix];
      float p2 = pnn[((2*NB+b)*10+c)*HW+pix];
      float p3 = pnn[((3*NB+b)*10+c)*HW+pix];
      float p4 = pnn[((4*NB+b)*10+c)*HW+pix];
      float p5 = pnn[((5*NB+b)*10+c)*HW+pix];
      a0 += Wa0[c]*p1;
      a1 += Wa1[c]*p0 + Wa1[10+c]*p2 + Wa1[20+c]*p3 + Wa1[30+c]*p4;
      a2 += Wa2[c]*p1;
      a3 += Wa3[c]*p1;
      a4 += Wa4[c]*p1 + Wa4[10+c]*p5;
      a5 += Wa5[c]*p4;
    }
    out[OFF_F + (0*NB+b)*HW + pix] = sig_(a0);
    out[OFF_F + (1*NB+b)*HW + pix] = sig_(a1);
    out[OFF_F + (2*NB+b)*HW + pix] = sig_(a2);
    out[OFF_F + (3*NB+b)*HW + pix] = sig_(a3);
    out[OFF_F + (4*NB+b)*HW + pix] = sig_(a4);
    out[OFF_F + (5*NB+b)*HW + pix] = sig_(a5);
  }

  // ---- decomposition messages: relation(cat([parent*a, child])) ----
  for (int n=0;n<6;n++){           // runtime loop (uniform n); arrays stay reg-indexed
    float a = (n==0)?au[1]:(n==1)?au[2]:(n==2)?au[3]:(n==3)?au[4]:(n==4)?al[1]:al[2];
    float x20[20];
    if (n<4){
#pragma unroll
      for (int c=0;c<10;c++) x20[c]=h0[c]*a;
    } else {
#pragma unroll
      for (int c=0;c<10;c++) x20[c]=h1[c]*a;
    }
#pragma unroll
    for (int c=0;c<10;c++) x20[10+c] = pnn[((n*NB+b)*10+c)*HW+pix];
    float h20[20];
#pragma unroll
    for (int o=0;o<20;o++){
      float acc=0.f;
#pragma unroll
      for (int c=0;c<20;c++) acc += Wd1[o*20+c]*x20[c];
      h20[o] = fmaxf(acc*s1v[o]+t1v[o], 0.f);
    }
#pragma unroll
    for (int o=0;o<10;o++){
      float acc=0.f;
#pragma unroll
      for (int c=0;c<20;c++) acc += Wd2[o*20+c]*h20[c];
      wmsg[((n*NB+b)*10+o)*HW + pix] = fmaxf(acc*s2v[o]+t2v[o], 0.f);
    }
  }
}

// ---------------------------------------------------------------------------
// Kernel B: projection  message += relu((2-att)*[W_proj . xp]*s + t)
// grid 256 x 256 threads, one thread per pixel; W_proj via uniform (scalar) loads
// ---------------------------------------------------------------------------
__global__ __launch_bounds__(256)
void k_proj(const float* __restrict__ xp, const float* __restrict__ Wp,
            const float* __restrict__ ps, const float* __restrict__ pt,
            const float* __restrict__ outf, float* __restrict__ wmsg)
{
  const int g   = blockIdx.x*256 + threadIdx.x;
  const int b   = g >> 14;
  const int pix = g & 16383;

  float z[60];
#pragma unroll
  for (int k=0;k<60;k++) z[k]=0.f;

  const float* xb = xp + (size_t)b*256*HW + pix;
  for (int cq=0; cq<64; cq++){
    float xv0 = xb[(size_t)(cq*4+0)*HW];
    float xv1 = xb[(size_t)(cq*4+1)*HW];
    float xv2 = xb[(size_t)(cq*4+2)*HW];
    float xv3 = xb[(size_t)(cq*4+3)*HW];
#pragma unroll
    for (int k=0;k<60;k++){
      float4 w = *reinterpret_cast<const float4*>(Wp + k*256 + cq*4);  // uniform -> s_load
      z[k] += xv0*w.x + xv1*w.y + xv2*w.z + xv3*w.w;
    }
  }

  float att[6];
#pragma unroll
  for (int n=0;n<6;n++) att[n] = outf[OFF_F + (n*NB+b)*HW + pix];

#pragma unroll
  for (int n=0;n<6;n++){
    float f = 2.f - att[n];
#pragma unroll
    for (int o=0;o<10;o++){
      const int k = n*10+o;
      float pr = fmaxf(f*z[k]*ps[k] + pt[k], 0.f);
      wmsg[((n*NB+b)*10+o)*HW + pix] += pr;
    }
  }
}

// ---------------------------------------------------------------------------
// Kernel C: GRU gates: gates = sigmoid(conv3x3(cat([msg, h]), Wg)+bg)
// store rh = r*h and u.  grid 1536 blocks (6 nodes x 4 batch x 64 row-pairs)
// ---------------------------------------------------------------------------
__global__ __launch_bounds__(256)
void k_gru_gates(const float* __restrict__ pnn, const float* __restrict__ Wg,
                 const float* __restrict__ bg,
                 const float* __restrict__ wmsg, float* __restrict__ wrh,
                 float* __restrict__ wu)
{
  const int bi  = blockIdx.x;
  const int n   = bi >> 8;
  const int rem = bi & 255;
  const int b   = rem >> 6;
  const int y   = ((rem & 63) << 1) + (threadIdx.x >> 7);
  const int x   = threadIdx.x & 127;
  const int base_nb = (n*NB+b)*10;
  const float* msgb = wmsg + (size_t)base_nb*HW;
  const float* pb   = pnn  + (size_t)base_nb*HW;
  const float* W    = Wg + n*3600;

  float acc[20];
#pragma unroll
  for (int o=0;o<20;o++) acc[o]=bg[n*20+o];

  for (int c0=0;c0<20;c0+=5){      // runtime chunk loop; 4 x (45 loads + 900 FMA)
    const float* base0 = (c0<10)? (msgb + c0*HW) : (pb + (c0-10)*HW);
    float v[5][9];
#pragma unroll
    for (int ii=0;ii<5;ii++){
      const float* basei = base0 + ii*HW;
#pragma unroll
      for (int dy=0;dy<3;dy++){
        const int yy = y+dy-1;
        const bool yok = ((unsigned)yy) < 128u;
#pragma unroll
        for (int dx=0;dx<3;dx++){
          const int xx = x+dx-1;
          v[ii][dy*3+dx] = (yok && ((unsigned)xx)<128u) ? basei[yy*WID+xx] : 0.f;
        }
      }
    }
    const float* Wb = W + c0*9;    // uniform -> s_load
#pragma unroll
    for (int o=0;o<20;o++){
      float a=acc[o];
#pragma unroll
      for (int ii=0;ii<5;ii++)
#pragma unroll
        for (int t=0;t<9;t++)
          a += v[ii][t]*Wb[o*180 + ii*9 + t];
      acc[o]=a;
    }
  }

  const int pix = y*WID+x;
#pragma unroll
  for (int o=0;o<10;o++){
    float r = sig_(acc[o]);
    float u = sig_(acc[10+o]);
    wrh[(size_t)(base_nb+o)*HW + pix] = r * pb[o*HW+pix];
    wu [(size_t)(base_nb+o)*HW + pix] = u;
  }
}

// ---------------------------------------------------------------------------
// Kernel D: candidate conv + GRU blend -> xp_new (out offset 0)
// ---------------------------------------------------------------------------
__global__ __launch_bounds__(256)
void k_gru_out(const float* __restrict__ pnn, const float* __restrict__ Wc,
               const float* __restrict__ bc,
               const float* __restrict__ wmsg, const float* __restrict__ wrh,
               const float* __restrict__ wu, float* __restrict__ out)
{
  const int bi  = blockIdx.x;
  const int n   = bi >> 8;
  const int rem = bi & 255;
  const int b   = rem >> 6;
  const int y   = ((rem & 63) << 1) + (threadIdx.x >> 7);
  const int x   = threadIdx.x & 127;
  const int base_nb = (n*NB+b)*10;
  const float* msgb = wmsg + (size_t)base_nb*HW;
  const float* rhb  = wrh  + (size_t)base_nb*HW;
  const float* pb   = pnn  + (size_t)base_nb*HW;
  const float* W    = Wc + n*1800;

  float acc[10];
#pragma unroll
  for (int o=0;o<10;o++) acc[o]=bc[n*10+o];

  for (int c0=0;c0<20;c0+=5){
    const float* base0 = (c0<10)? (msgb + c0*HW) : (rhb + (c0-10)*HW);
    float v[5][9];
#pragma unroll
    for (int ii=0;ii<5;ii++){
      const float* basei = base0 + ii*HW;
#pragma unroll
      for (int dy=0;dy<3;dy++){
        const int yy = y+dy-1;
        const bool yok = ((unsigned)yy) < 128u;
#pragma unroll
        for (int dx=0;dx<3;dx++){
          const int xx = x+dx-1;
          v[ii][dy*3+dx] = (yok && ((unsigned)xx)<128u) ? basei[yy*WID+xx] : 0.f;
        }
      }
    }
    const float* Wb = W + c0*9;
#pragma unroll
    for (int o=0;o<10;o++){
      float a=acc[o];
#pragma unroll
      for (int ii=0;ii<5;ii++)
#pragma unroll
        for (int t=0;t<9;t++)
          a += v[ii][t]*Wb[o*180 + ii*9 + t];
      acc[o]=a;
    }
  }

  const int pix = y*WID+x;
#pragma unroll
  for (int o=0;o<10;o++){
    float u  = wu[(size_t)(base_nb+o)*HW + pix];
    float h  = pb[o*HW+pix];
    float cd = tanh_(acc[o]);
    out[(size_t)(base_nb+o)*HW + pix] = (1.f-u)*h + u*cd;
  }
}

// ---------------------------------------------------------------------------
extern "C" void kernel_launch(void* const* d_in, const int* in_sizes, int n_in,
                              void* d_out, int out_size, void* d_ws, size_t ws_size,
                              hipStream_t stream)
{
  (void)in_sizes; (void)n_in; (void)out_size; (void)ws_size;
  // input order per setup_inputs(): 0 f_node (unused), 1 h_nodes, 2 p_nodes, 3 xp,
  // 4 W_dau, 5 b_dau, 6 W_dal, 7 b_dal, 8 W_dec1, 9 dec1_s, 10 dec1_t,
  // 11 W_dec2, 12 dec2_s, 13 dec2_t, 14..19 W_att0..5, 20 b_att,
  // 21 W_proj, 22 proj_s, 23 proj_t, 24 Wg, 25 bg, 26 Wc, 27 bc
  const float* hn   = (const float*)d_in[1];
  const float* pnn  = (const float*)d_in[2];
  const float* xp   = (const float*)d_in[3];
  const float* Wdau = (const float*)d_in[4];
  const float* bdau = (const float*)d_in[5];
  const float* Wdal = (const float*)d_in[6];
  const float* bdal = (const float*)d_in[7];
  const float* Wd1  = (const float*)d_in[8];
  const float* s1v  = (const float*)d_in[9];
  const float* t1v  = (const float*)d_in[10];
  const float* Wd2  = (const float*)d_in[11];
  const float* s2v  = (const float*)d_in[12];
  const float* t2v  = (const float*)d_in[13];
  const float* Wa0  = (const float*)d_in[14];
  const float* Wa1  = (const float*)d_in[15];
  const float* Wa2  = (const float*)d_in[16];
  const float* Wa3  = (const float*)d_in[17];
  const float* Wa4  = (const float*)d_in[18];
  const float* Wa5  = (const float*)d_in[19];
  const float* batt = (const float*)d_in[20];
  const float* Wp   = (const float*)d_in[21];
  const float* ps   = (const float*)d_in[22];
  const float* pt   = (const float*)d_in[23];
  const float* Wg   = (const float*)d_in[24];
  const float* bg   = (const float*)d_in[25];
  const float* Wc   = (const float*)d_in[26];
  const float* bc   = (const float*)d_in[27];

  float* out = (float*)d_out;
  float* wsf = (float*)d_ws;
  float* ws_msg = wsf;               // [6*4*10*HW] = 3,932,160 floats
  float* ws_rh  = wsf + 3932160;     // same size
  float* ws_u   = wsf + 7864320;     // same size  (total 47.2 MB)

  k_att_dec<<<dim3(256), dim3(256), 0, stream>>>(hn, pnn, Wdau, bdau, Wdal, bdal,
      Wd1, s1v, t1v, Wd2, s2v, t2v, Wa0, Wa1, Wa2, Wa3, Wa4, Wa5, batt, out, ws_msg);
  k_proj<<<dim3(256), dim3(256), 0, stream>>>(xp, Wp, ps, pt, (const float*)d_out, ws_msg);
  k_gru_gates<<<dim3(1536), dim3(256), 0, stream>>>(pnn, Wg, bg, ws_msg, ws_rh, ws_u);
  k_gru_out<<<dim3(1536), dim3(256), 0, stream>>>(pnn, Wc, bc, ws_msg, ws_rh, ws_u, out);
}

// Round 3
// 230.173 us; speedup vs baseline: 1.6013x; 1.6013x over previous
//
#include <hip/hip_runtime.h>
#include <math.h>

#define HW    16384
#define WID   128
#define NB    4
// output section offsets (floats)
#define OFF_U 3932160
#define OFF_L 4259840
#define OFF_F 4456448

typedef __attribute__((ext_vector_type(8))) short  short8_t;
typedef __attribute__((ext_vector_type(4))) float  float4_t;

__device__ __forceinline__ float sig_(float x)  { return 1.f/(1.f+__expf(-x)); }
__device__ __forceinline__ float tanh_(float x) { float e=__expf(2.f*x); return 1.f - 2.f/(e+1.f); }
__device__ __forceinline__ unsigned short f2bf(float x){          // RNE fp32->bf16
  unsigned u = __float_as_uint(x);
  return (unsigned short)((u + 0x7fffu + ((u>>16)&1u)) >> 16);
}

// ---------------------------------------------------------------------------
// Kernel A: node-split (grid 1536 = 6 nodes x 256 pixel-blocks, 24 waves/CU)
// decomp maps + softmax att (redundant per node), Fdep att, decomp message
// ---------------------------------------------------------------------------
__global__ __launch_bounds__(256)
void k_att_dec(const float* __restrict__ hn, const float* __restrict__ pnn,
               const float* __restrict__ Wdau, const float* __restrict__ bdau,
               const float* __restrict__ Wdal, const float* __restrict__ bdal,
               const float* __restrict__ Wd1, const float* __restrict__ s1v, const float* __restrict__ t1v,
               const float* __restrict__ Wd2, const float* __restrict__ s2v, const float* __restrict__ t2v,
               const float* __restrict__ Wa0, const float* __restrict__ Wa1, const float* __restrict__ Wa2,
               const float* __restrict__ Wa3, const float* __restrict__ Wa4, const float* __restrict__ Wa5,
               const float* __restrict__ batt,
               float* __restrict__ out, float* __restrict__ wmsg)
{
  const int n   = blockIdx.x >> 8;               // node 0..5 (block-uniform)
  const int g   = (blockIdx.x & 255)*256 + threadIdx.x;
  const int b   = g >> 14;
  const int pix = g & 16383;

  // parent hidden + decomposition attention weight for this node
  float h[10];
  float a;
  if (n < 4){
#pragma unroll
    for (int c=0;c<10;c++) h[c] = hn[(b*10+c)*HW + pix];
    float v[5]; float mx = -1e30f;
#pragma unroll
    for (int o=0;o<5;o++){
      float t = bdau[o];
#pragma unroll
      for (int c=0;c<10;c++) t += Wdau[o*10+c]*h[c];
      if (n==0) out[OFF_U + (b*5+o)*HW + pix] = t;
      v[o]=t; mx = fmaxf(mx,t);
    }
    float s=0.f;
#pragma unroll
    for (int o=0;o<5;o++){ v[o]=__expf(v[o]-mx); s+=v[o]; }
    a = v[n+1]/s;
  } else {
#pragma unroll
    for (int c=0;c<10;c++) h[c] = hn[((NB+b)*10+c)*HW + pix];
    float v[3]; float mx = -1e30f;
#pragma unroll
    for (int o=0;o<3;o++){
      float t = bdal[o];
#pragma unroll
      for (int c=0;c<10;c++) t += Wdal[o*10+c]*h[c];
      if (n==4) out[OFF_L + (b*3+o)*HW + pix] = t;
      v[o]=t; mx = fmaxf(mx,t);
    }
    float s=0.f;
#pragma unroll
    for (int o=0;o<3;o++){ v[o]=__expf(v[o]-mx); s+=v[o]; }
    a = v[n-3]/s;
  }

  // child features
  float child[10];
#pragma unroll
  for (int c=0;c<10;c++) child[c] = pnn[((n*NB+b)*10+c)*HW + pix];

  // Fdep attention for this node (PART_LIST_LIST = [[1],[0,2,3,4],[1],[1],[1,5],[4]])
  float af = batt[n];
  if (n==0){
#pragma unroll
    for (int c=0;c<10;c++) af += Wa0[c]*pnn[((1*NB+b)*10+c)*HW+pix];
  } else if (n==1){
#pragma unroll
    for (int c=0;c<10;c++){
      af += Wa1[c]   *pnn[((0*NB+b)*10+c)*HW+pix];
      af += Wa1[10+c]*pnn[((2*NB+b)*10+c)*HW+pix];
      af += Wa1[20+c]*pnn[((3*NB+b)*10+c)*HW+pix];
      af += Wa1[30+c]*pnn[((4*NB+b)*10+c)*HW+pix];
    }
  } else if (n==2){
#pragma unroll
    for (int c=0;c<10;c++) af += Wa2[c]*pnn[((1*NB+b)*10+c)*HW+pix];
  } else if (n==3){
#pragma unroll
    for (int c=0;c<10;c++) af += Wa3[c]*pnn[((1*NB+b)*10+c)*HW+pix];
  } else if (n==4){
#pragma unroll
    for (int c=0;c<10;c++){
      af += Wa4[c]   *pnn[((1*NB+b)*10+c)*HW+pix];
      af += Wa4[10+c]*pnn[((5*NB+b)*10+c)*HW+pix];
    }
  } else {
#pragma unroll
    for (int c=0;c<10;c++) af += Wa5[c]*pnn[((4*NB+b)*10+c)*HW+pix];
  }
  out[OFF_F + (n*NB+b)*HW + pix] = sig_(af);

  // decomposition message: relation(cat([parent*a, child]))
  float x20[20];
#pragma unroll
  for (int c=0;c<10;c++){ x20[c]=h[c]*a; x20[10+c]=child[c]; }
  float h20[20];
#pragma unroll
  for (int o=0;o<20;o++){
    float acc=0.f;
#pragma unroll
    for (int c=0;c<20;c++) acc += Wd1[o*20+c]*x20[c];
    h20[o] = fmaxf(acc*s1v[o]+t1v[o], 0.f);
  }
#pragma unroll
  for (int o=0;o<10;o++){
    float acc=0.f;
#pragma unroll
    for (int c=0;c<20;c++) acc += Wd2[o*20+c]*h20[c];
    wmsg[((n*NB+b)*10+o)*HW + pix] = fmaxf(acc*s2v[o]+t2v[o], 0.f);
  }
}

// ---------------------------------------------------------------------------
// Kernel B: projection as bf16 MFMA GEMM.  D[60pad64 x 16px] = Wps . xp_tile
// block 512 thr (8 waves), grid 256; wave owns 2 pixel-tiles of 16.
// Weights (ps-folded, bf16) staged once per block to LDS (stride 264: 2-way bank).
// A-frags held in 128 VGPRs/wave.  Epilogue: relu((2-att)*z + pt), msg +=.
// ---------------------------------------------------------------------------
__global__ __launch_bounds__(512)
void k_proj(const float* __restrict__ xp, const float* __restrict__ Wp,
            const float* __restrict__ ps, const float* __restrict__ pt,
            const float* __restrict__ outf, float* __restrict__ wmsg)
{
  __shared__ unsigned short wlds[64*264];
  const int tid = threadIdx.x;

  // stage ps-folded bf16 weights (rows 60..63 zero)
  for (int e = tid; e < 64*256; e += 512){
    int row = e >> 8, c = e & 255;
    float v = (row < 60) ? Wp[row*256 + c] * ps[row] : 0.f;
    wlds[row*264 + c] = f2bf(v);
  }
  __syncthreads();

  const int l  = tid & 63;
  const int w  = tid >> 6;        // wave 0..7
  const int lr = l & 15;          // A row-in-frag / B col (pixel)
  const int lk = l >> 4;          // k-group 0..3

  // A fragments: wa[nfrag][kstep], k = kstep*32 + lk*8 + j (same map as B -> cancels)
  short8_t wa[4][8];
#pragma unroll
  for (int nf=0;nf<4;nf++)
#pragma unroll
    for (int ks=0;ks<8;ks++)
      wa[nf][ks] = *reinterpret_cast<const short8_t*>(&wlds[(nf*16+lr)*264 + ks*32 + lk*8]);

  for (int t=0; t<2; ++t){
    const int tile = blockIdx.x*16 + w*2 + t;
    const int P    = tile*16;
    const int b    = P >> 14;
    const int pixb = P & 16383;
    const int px   = pixb + lr;

    float4_t acc[4];
#pragma unroll
    for (int nf=0;nf<4;nf++){ acc[nf][0]=0.f; acc[nf][1]=0.f; acc[nf][2]=0.f; acc[nf][3]=0.f; }

    const float* xb = xp + (size_t)(b*256)*HW + px;
#pragma unroll
    for (int ks=0;ks<8;ks++){
      const int cb = ks*32 + lk*8;
      float v[8];
#pragma unroll
      for (int j=0;j<8;j++) v[j] = xb[(size_t)(cb+j)*HW];
      short8_t bf;
#pragma unroll
      for (int j=0;j<8;j++) bf[j] = (short)f2bf(v[j]);
#pragma unroll
      for (int nf=0;nf<4;nf++)
        acc[nf] = __builtin_amdgcn_mfma_f32_16x16x32_bf16(wa[nf][ks], bf, acc[nf], 0,0,0);
    }

    // epilogue: row = nf*16 + lk*4 + j  (C/D layout: col=lane&15, row=(lane>>4)*4+reg)
#pragma unroll
    for (int nf=0;nf<4;nf++){
#pragma unroll
      for (int j=0;j<4;j++){
        const int row = nf*16 + lk*4 + j;
        if (row < 60){
          const unsigned nn = (unsigned)row / 10u;
          const int o = row - (int)nn*10;
          float att = outf[OFF_F + (nn*NB+b)*HW + pixb + lr];
          float val = fmaxf((2.f - att)*acc[nf][j] + pt[row], 0.f);
          size_t idx = ((size_t)((nn*NB+b)*10 + o))*HW + pixb + lr;
          wmsg[idx] += val;
        }
      }
    }
  }
}

// ---------------------------------------------------------------------------
// Kernel C: GRU gates conv (unchanged)
// ---------------------------------------------------------------------------
__global__ __launch_bounds__(256)
void k_gru_gates(const float* __restrict__ pnn, const float* __restrict__ Wg,
                 const float* __restrict__ bg,
                 const float* __restrict__ wmsg, float* __restrict__ wrh,
                 float* __restrict__ wu)
{
  const int bi  = blockIdx.x;
  const int n   = bi >> 8;
  const int rem = bi & 255;
  const int b   = rem >> 6;
  const int y   = ((rem & 63) << 1) + (threadIdx.x >> 7);
  const int x   = threadIdx.x & 127;
  const int base_nb = (n*NB+b)*10;
  const float* msgb = wmsg + (size_t)base_nb*HW;
  const float* pb   = pnn  + (size_t)base_nb*HW;
  const float* W    = Wg + n*3600;

  float acc[20];
#pragma unroll
  for (int o=0;o<20;o++) acc[o]=bg[n*20+o];

  for (int c0=0;c0<20;c0+=5){
    const float* base0 = (c0<10)? (msgb + c0*HW) : (pb + (c0-10)*HW);
    float v[5][9];
#pragma unroll
    for (int ii=0;ii<5;ii++){
      const float* basei = base0 + ii*HW;
#pragma unroll
      for (int dy=0;dy<3;dy++){
        const int yy = y+dy-1;
        const bool yok = ((unsigned)yy) < 128u;
#pragma unroll
        for (int dx=0;dx<3;dx++){
          const int xx = x+dx-1;
          v[ii][dy*3+dx] = (yok && ((unsigned)xx)<128u) ? basei[yy*WID+xx] : 0.f;
        }
      }
    }
    const float* Wb = W + c0*9;
#pragma unroll
    for (int o=0;o<20;o++){
      float a=acc[o];
#pragma unroll
      for (int ii=0;ii<5;ii++)
#pragma unroll
        for (int t=0;t<9;t++)
          a += v[ii][t]*Wb[o*180 + ii*9 + t];
      acc[o]=a;
    }
  }

  const int pix = y*WID+x;
#pragma unroll
  for (int o=0;o<10;o++){
    float r = sig_(acc[o]);
    float u = sig_(acc[10+o]);
    wrh[(size_t)(base_nb+o)*HW + pix] = r * pb[o*HW+pix];
    wu [(size_t)(base_nb+o)*HW + pix] = u;
  }
}

// ---------------------------------------------------------------------------
// Kernel D: candidate conv + GRU blend (unchanged)
// ---------------------------------------------------------------------------
__global__ __launch_bounds__(256)
void k_gru_out(const float* __restrict__ pnn, const float* __restrict__ Wc,
               const float* __restrict__ bc,
               const float* __restrict__ wmsg, const float* __restrict__ wrh,
               const float* __restrict__ wu, float* __restrict__ out)
{
  const int bi  = blockIdx.x;
  const int n   = bi >> 8;
  const int rem = bi & 255;
  const int b   = rem >> 6;
  const int y   = ((rem & 63) << 1) + (threadIdx.x >> 7);
  const int x   = threadIdx.x & 127;
  const int base_nb = (n*NB+b)*10;
  const float* msgb = wmsg + (size_t)base_nb*HW;
  const float* rhb  = wrh  + (size_t)base_nb*HW;
  const float* pb   = pnn  + (size_t)base_nb*HW;
  const float* W    = Wc + n*1800;

  float acc[10];
#pragma unroll
  for (int o=0;o<10;o++) acc[o]=bc[n*10+o];

  for (int c0=0;c0<20;c0+=5){
    const float* base0 = (c0<10)? (msgb + c0*HW) : (rhb + (c0-10)*HW);
    float v[5][9];
#pragma unroll
    for (int ii=0;ii<5;ii++){
      const float* basei = base0 + ii*HW;
#pragma unroll
      for (int dy=0;dy<3;dy++){
        const int yy = y+dy-1;
        const bool yok = ((unsigned)yy) < 128u;
#pragma unroll
        for (int dx=0;dx<3;dx++){
          const int xx = x+dx-1;
          v[ii][dy*3+dx] = (yok && ((unsigned)xx)<128u) ? basei[yy*WID+xx] : 0.f;
        }
      }
    }
    const float* Wb = W + c0*9;
#pragma unroll
    for (int o=0;o<10;o++){
      float a=acc[o];
#pragma unroll
      for (int ii=0;ii<5;ii++)
#pragma unroll
        for (int t=0;t<9;t++)
          a += v[ii][t]*Wb[o*180 + ii*9 + t];
      acc[o]=a;
    }
  }

  const int pix = y*WID+x;
#pragma unroll
  for (int o=0;o<10;o++){
    float u  = wu[(size_t)(base_nb+o)*HW + pix];
    float h  = pb[o*HW+pix];
    float cd = tanh_(acc[o]);
    out[(size_t)(base_nb+o)*HW + pix] = (1.f-u)*h + u*cd;
  }
}

// ---------------------------------------------------------------------------
extern "C" void kernel_launch(void* const* d_in, const int* in_sizes, int n_in,
                              void* d_out, int out_size, void* d_ws, size_t ws_size,
                              hipStream_t stream)
{
  (void)in_sizes; (void)n_in; (void)out_size; (void)ws_size;
  const float* hn   = (const float*)d_in[1];
  const float* pnn  = (const float*)d_in[2];
  const float* xp   = (const float*)d_in[3];
  const float* Wdau = (const float*)d_in[4];
  const float* bdau = (const float*)d_in[5];
  const float* Wdal = (const float*)d_in[6];
  const float* bdal = (const float*)d_in[7];
  const float* Wd1  = (const float*)d_in[8];
  const float* s1v  = (const float*)d_in[9];
  const float* t1v  = (const float*)d_in[10];
  const float* Wd2  = (const float*)d_in[11];
  const float* s2v  = (const float*)d_in[12];
  const float* t2v  = (const float*)d_in[13];
  const float* Wa0  = (const float*)d_in[14];
  const float* Wa1  = (const float*)d_in[15];
  const float* Wa2  = (const float*)d_in[16];
  const float* Wa3  = (const float*)d_in[17];
  const float* Wa4  = (const float*)d_in[18];
  const float* Wa5  = (const float*)d_in[19];
  const float* batt = (const float*)d_in[20];
  const float* Wp   = (const float*)d_in[21];
  const float* ps   = (const float*)d_in[22];
  const float* pt   = (const float*)d_in[23];
  const float* Wg   = (const float*)d_in[24];
  const float* bg   = (const float*)d_in[25];
  const float* Wc   = (const float*)d_in[26];
  const float* bc   = (const float*)d_in[27];

  float* out = (float*)d_out;
  float* wsf = (float*)d_ws;
  float* ws_msg = wsf;               // [6*4*10*HW] floats
  float* ws_rh  = wsf + 3932160;
  float* ws_u   = wsf + 7864320;

  k_att_dec<<<dim3(1536), dim3(256), 0, stream>>>(hn, pnn, Wdau, bdau, Wdal, bdal,
      Wd1, s1v, t1v, Wd2, s2v, t2v, Wa0, Wa1, Wa2, Wa3, Wa4, Wa5, batt, out, ws_msg);
  k_proj<<<dim3(256), dim3(512), 0, stream>>>(xp, Wp, ps, pt, (const float*)d_out, ws_msg);
  k_gru_gates<<<dim3(1536), dim3(256), 0, stream>>>(pnn, Wg, bg, ws_msg, ws_rh, ws_u);
  k_gru_out<<<dim3(1536), dim3(256), 0, stream>>>(pnn, Wc, bc, ws_msg, ws_rh, ws_u, out);
}

// Round 4
// 185.717 us; speedup vs baseline: 1.9846x; 1.2394x over previous
//
#include <hip/hip_runtime.h>
#include <math.h>

#define HW    16384
#define WID   128
#define NB    4
// output section offsets (floats)
#define OFF_U 3932160
#define OFF_L 4259840
#define OFF_F 4456448

// conv LDS tile geometry: 6 rows x 136 cols per channel, 10 channels
#define LROW 136
#define LCH  816      // 6*136
#define LDSN 8160     // 10*LCH floats = 32640 B -> 5 blocks/CU

typedef __attribute__((ext_vector_type(8))) short  short8_t;
typedef __attribute__((ext_vector_type(4))) float  float4_t;

__device__ __forceinline__ float sig_(float x)  { return 1.f/(1.f+__expf(-x)); }
__device__ __forceinline__ float tanh_(float x) { float e=__expf(2.f*x); return 1.f - 2.f/(e+1.f); }
__device__ __forceinline__ unsigned short f2bf(float x){          // RNE fp32->bf16
  unsigned u = __float_as_uint(x);
  return (unsigned short)((u + 0x7fffu + ((u>>16)&1u)) >> 16);
}

// ---------------------------------------------------------------------------
// Kernel A: node-split (grid 1536 = 6 nodes x 256 pixel-blocks)
// ---------------------------------------------------------------------------
__global__ __launch_bounds__(256)
void k_att_dec(const float* __restrict__ hn, const float* __restrict__ pnn,
               const float* __restrict__ Wdau, const float* __restrict__ bdau,
               const float* __restrict__ Wdal, const float* __restrict__ bdal,
               const float* __restrict__ Wd1, const float* __restrict__ s1v, const float* __restrict__ t1v,
               const float* __restrict__ Wd2, const float* __restrict__ s2v, const float* __restrict__ t2v,
               const float* __restrict__ Wa0, const float* __restrict__ Wa1, const float* __restrict__ Wa2,
               const float* __restrict__ Wa3, const float* __restrict__ Wa4, const float* __restrict__ Wa5,
               const float* __restrict__ batt,
               float* __restrict__ out, float* __restrict__ wmsg)
{
  const int n   = blockIdx.x >> 8;               // node 0..5 (block-uniform)
  const int g   = (blockIdx.x & 255)*256 + threadIdx.x;
  const int b   = g >> 14;
  const int pix = g & 16383;

  float h[10];
  float a;
  if (n < 4){
#pragma unroll
    for (int c=0;c<10;c++) h[c] = hn[(b*10+c)*HW + pix];
    float v[5]; float mx = -1e30f;
#pragma unroll
    for (int o=0;o<5;o++){
      float t = bdau[o];
#pragma unroll
      for (int c=0;c<10;c++) t += Wdau[o*10+c]*h[c];
      if (n==0) out[OFF_U + (b*5+o)*HW + pix] = t;
      v[o]=t; mx = fmaxf(mx,t);
    }
    float s=0.f;
#pragma unroll
    for (int o=0;o<5;o++){ v[o]=__expf(v[o]-mx); s+=v[o]; }
    a = v[n+1]/s;
  } else {
#pragma unroll
    for (int c=0;c<10;c++) h[c] = hn[((NB+b)*10+c)*HW + pix];
    float v[3]; float mx = -1e30f;
#pragma unroll
    for (int o=0;o<3;o++){
      float t = bdal[o];
#pragma unroll
      for (int c=0;c<10;c++) t += Wdal[o*10+c]*h[c];
      if (n==4) out[OFF_L + (b*3+o)*HW + pix] = t;
      v[o]=t; mx = fmaxf(mx,t);
    }
    float s=0.f;
#pragma unroll
    for (int o=0;o<3;o++){ v[o]=__expf(v[o]-mx); s+=v[o]; }
    a = v[n-3]/s;
  }

  float child[10];
#pragma unroll
  for (int c=0;c<10;c++) child[c] = pnn[((n*NB+b)*10+c)*HW + pix];

  float af = batt[n];
  if (n==0){
#pragma unroll
    for (int c=0;c<10;c++) af += Wa0[c]*pnn[((1*NB+b)*10+c)*HW+pix];
  } else if (n==1){
#pragma unroll
    for (int c=0;c<10;c++){
      af += Wa1[c]   *pnn[((0*NB+b)*10+c)*HW+pix];
      af += Wa1[10+c]*pnn[((2*NB+b)*10+c)*HW+pix];
      af += Wa1[20+c]*pnn[((3*NB+b)*10+c)*HW+pix];
      af += Wa1[30+c]*pnn[((4*NB+b)*10+c)*HW+pix];
    }
  } else if (n==2){
#pragma unroll
    for (int c=0;c<10;c++) af += Wa2[c]*pnn[((1*NB+b)*10+c)*HW+pix];
  } else if (n==3){
#pragma unroll
    for (int c=0;c<10;c++) af += Wa3[c]*pnn[((1*NB+b)*10+c)*HW+pix];
  } else if (n==4){
#pragma unroll
    for (int c=0;c<10;c++){
      af += Wa4[c]   *pnn[((1*NB+b)*10+c)*HW+pix];
      af += Wa4[10+c]*pnn[((5*NB+b)*10+c)*HW+pix];
    }
  } else {
#pragma unroll
    for (int c=0;c<10;c++) af += Wa5[c]*pnn[((4*NB+b)*10+c)*HW+pix];
  }
  out[OFF_F + (n*NB+b)*HW + pix] = sig_(af);

  float x20[20];
#pragma unroll
  for (int c=0;c<10;c++){ x20[c]=h[c]*a; x20[10+c]=child[c]; }
  float h20[20];
#pragma unroll
  for (int o=0;o<20;o++){
    float acc=0.f;
#pragma unroll
    for (int c=0;c<20;c++) acc += Wd1[o*20+c]*x20[c];
    h20[o] = fmaxf(acc*s1v[o]+t1v[o], 0.f);
  }
#pragma unroll
  for (int o=0;o<10;o++){
    float acc=0.f;
#pragma unroll
    for (int c=0;c<20;c++) acc += Wd2[o*20+c]*h20[c];
    wmsg[((n*NB+b)*10+o)*HW + pix] = fmaxf(acc*s2v[o]+t2v[o], 0.f);
  }
}

// ---------------------------------------------------------------------------
// Kernel B: projection as bf16 MFMA GEMM (unchanged from round 3)
// ---------------------------------------------------------------------------
__global__ __launch_bounds__(512)
void k_proj(const float* __restrict__ xp, const float* __restrict__ Wp,
            const float* __restrict__ ps, const float* __restrict__ pt,
            const float* __restrict__ outf, float* __restrict__ wmsg)
{
  __shared__ unsigned short wlds[64*264];
  const int tid = threadIdx.x;

  for (int e = tid; e < 64*256; e += 512){
    int row = e >> 8, c = e & 255;
    float v = (row < 60) ? Wp[row*256 + c] * ps[row] : 0.f;
    wlds[row*264 + c] = f2bf(v);
  }
  __syncthreads();

  const int l  = tid & 63;
  const int w  = tid >> 6;
  const int lr = l & 15;
  const int lk = l >> 4;

  short8_t wa[4][8];
#pragma unroll
  for (int nf=0;nf<4;nf++)
#pragma unroll
    for (int ks=0;ks<8;ks++)
      wa[nf][ks] = *reinterpret_cast<const short8_t*>(&wlds[(nf*16+lr)*264 + ks*32 + lk*8]);

  for (int t=0; t<2; ++t){
    const int tile = blockIdx.x*16 + w*2 + t;
    const int P    = tile*16;
    const int b    = P >> 14;
    const int pixb = P & 16383;
    const int px   = pixb + lr;

    float4_t acc[4];
#pragma unroll
    for (int nf=0;nf<4;nf++){ acc[nf][0]=0.f; acc[nf][1]=0.f; acc[nf][2]=0.f; acc[nf][3]=0.f; }

    const float* xb = xp + (size_t)(b*256)*HW + px;
#pragma unroll
    for (int ks=0;ks<8;ks++){
      const int cb = ks*32 + lk*8;
      float v[8];
#pragma unroll
      for (int j=0;j<8;j++) v[j] = xb[(size_t)(cb+j)*HW];
      short8_t bf;
#pragma unroll
      for (int j=0;j<8;j++) bf[j] = (short)f2bf(v[j]);
#pragma unroll
      for (int nf=0;nf<4;nf++)
        acc[nf] = __builtin_amdgcn_mfma_f32_16x16x32_bf16(wa[nf][ks], bf, acc[nf], 0,0,0);
    }

#pragma unroll
    for (int nf=0;nf<4;nf++){
#pragma unroll
      for (int j=0;j<4;j++){
        const int row = nf*16 + lk*4 + j;
        if (row < 60){
          const unsigned nn = (unsigned)row / 10u;
          const int o = row - (int)nn*10;
          float att = outf[OFF_F + (nn*NB+b)*HW + pixb + lr];
          float val = fmaxf((2.f - att)*acc[nf][j] + pt[row], 0.f);
          size_t idx = ((size_t)((nn*NB+b)*10 + o))*HW + pixb + lr;
          wmsg[idx] += val;
        }
      }
    }
  }
}

// ---------------------------------------------------------------------------
// Kernel C: GRU gates conv, LDS-tiled.  Block = (n, b, 4-row tile), 256 thr,
// 2 vertically-adjacent pixels/thread.  Tap loop has NO bounds checks:
// x-halo = zeroed LDS cols 3/132, y-halo zero-filled at stage time.
// ---------------------------------------------------------------------------
__global__ __launch_bounds__(256, 4)
void k_gru_gates(const float* __restrict__ pnn, const float* __restrict__ Wg,
                 const float* __restrict__ bg,
                 const float* __restrict__ wmsg, float* __restrict__ wrh,
                 float* __restrict__ wu)
{
  __shared__ float lds[LDSN];
  const int bi = blockIdx.x;
  const int n  = bi >> 7;             // 6
  const int b  = (bi >> 5) & 3;       // 4
  const int y0 = (bi & 31) * 4;       // 32 tiles of 4 rows
  const int tid = threadIdx.x;
  const int x  = tid & 127;
  const int r  = tid >> 7;            // 0/1 (wave-uniform)

  const int base_nb = (n*NB+b)*10;
  const float* msgb = wmsg + (size_t)base_nb*HW;
  const float* pb   = pnn  + (size_t)base_nb*HW;
  const float* W    = Wg + n*3600;

  float acc0[20], acc1[20];
#pragma unroll
  for (int o=0;o<20;o++){ float bv = bg[n*20+o]; acc0[o]=bv; acc1[o]=bv; }

  for (int half=0; half<2; ++half){
    const float* src = (half==0)? msgb : pb;
    __syncthreads();
    for (int e = tid; e < 1920; e += 256){
      const int ch  = e / 192;
      const int rem = e - ch*192;
      const int r6  = rem >> 5;
      const int q   = rem & 31;
      const int yy  = y0 - 1 + r6;
      float4 v = make_float4(0.f,0.f,0.f,0.f);
      if ((unsigned)yy < 128u)
        v = *reinterpret_cast<const float4*>(src + (size_t)ch*HW + yy*WID + q*4);
      *reinterpret_cast<float4*>(&lds[ch*LCH + r6*LROW + 4 + q*4]) = v;
    }
    if (tid < 120){
      const int ch = tid/12, k2 = tid%12, rr = k2>>1, side = k2&1;
      lds[ch*LCH + rr*LROW + 3 + side*129] = 0.f;   // cols 3 and 132
    }
    __syncthreads();

    for (int ch=0; ch<10; ++ch){
      float v[4][3];
#pragma unroll
      for (int rr=0;rr<4;rr++)
#pragma unroll
        for (int c=0;c<3;c++)
          v[rr][c] = lds[ch*LCH + (2*r+rr)*LROW + x+3+c];
      const float* Wc0 = W + (half*10+ch)*9;
#pragma unroll
      for (int o=0;o<20;o++){
        const float* w9 = Wc0 + o*180;
        float a0=acc0[o], a1=acc1[o];
#pragma unroll
        for (int dy=0;dy<3;dy++)
#pragma unroll
          for (int c=0;c<3;c++){
            const float wv = w9[dy*3+c];
            a0 += v[dy][c]  *wv;
            a1 += v[dy+1][c]*wv;
          }
        acc0[o]=a0; acc1[o]=a1;
      }
    }
  }

  const int pix0 = (y0 + 2*r)*WID + x;
  const int pix1 = pix0 + WID;
#pragma unroll
  for (int o=0;o<10;o++){
    const size_t idx = (size_t)(base_nb+o)*HW;
    float r0 = sig_(acc0[o]), u0 = sig_(acc0[10+o]);
    float r1 = sig_(acc1[o]), u1 = sig_(acc1[10+o]);
    wrh[idx+pix0] = r0 * pb[o*HW+pix0];
    wrh[idx+pix1] = r1 * pb[o*HW+pix1];
    wu [idx+pix0] = u0;
    wu [idx+pix1] = u1;
  }
}

// ---------------------------------------------------------------------------
// Kernel D: candidate conv + GRU blend, same LDS tiling
// ---------------------------------------------------------------------------
__global__ __launch_bounds__(256, 4)
void k_gru_out(const float* __restrict__ pnn, const float* __restrict__ Wc,
               const float* __restrict__ bc,
               const float* __restrict__ wmsg, const float* __restrict__ wrh,
               const float* __restrict__ wu, float* __restrict__ out)
{
  __shared__ float lds[LDSN];
  const int bi = blockIdx.x;
  const int n  = bi >> 7;
  const int b  = (bi >> 5) & 3;
  const int y0 = (bi & 31) * 4;
  const int tid = threadIdx.x;
  const int x  = tid & 127;
  const int r  = tid >> 7;

  const int base_nb = (n*NB+b)*10;
  const float* msgb = wmsg + (size_t)base_nb*HW;
  const float* rhb  = wrh  + (size_t)base_nb*HW;
  const float* pb   = pnn  + (size_t)base_nb*HW;
  const float* W    = Wc + n*1800;

  float acc0[10], acc1[10];
#pragma unroll
  for (int o=0;o<10;o++){ float bv = bc[n*10+o]; acc0[o]=bv; acc1[o]=bv; }

  for (int half=0; half<2; ++half){
    const float* src = (half==0)? msgb : rhb;
    __syncthreads();
    for (int e = tid; e < 1920; e += 256){
      const int ch  = e / 192;
      const int rem = e - ch*192;
      const int r6  = rem >> 5;
      const int q   = rem & 31;
      const int yy  = y0 - 1 + r6;
      float4 v = make_float4(0.f,0.f,0.f,0.f);
      if ((unsigned)yy < 128u)
        v = *reinterpret_cast<const float4*>(src + (size_t)ch*HW + yy*WID + q*4);
      *reinterpret_cast<float4*>(&lds[ch*LCH + r6*LROW + 4 + q*4]) = v;
    }
    if (tid < 120){
      const int ch = tid/12, k2 = tid%12, rr = k2>>1, side = k2&1;
      lds[ch*LCH + rr*LROW + 3 + side*129] = 0.f;
    }
    __syncthreads();

    for (int ch=0; ch<10; ++ch){
      float v[4][3];
#pragma unroll
      for (int rr=0;rr<4;rr++)
#pragma unroll
        for (int c=0;c<3;c++)
          v[rr][c] = lds[ch*LCH + (2*r+rr)*LROW + x+3+c];
      const float* Wc0 = W + (half*10+ch)*9;
#pragma unroll
      for (int o=0;o<10;o++){
        const float* w9 = Wc0 + o*180;
        float a0=acc0[o], a1=acc1[o];
#pragma unroll
        for (int dy=0;dy<3;dy++)
#pragma unroll
          for (int c=0;c<3;c++){
            const float wv = w9[dy*3+c];
            a0 += v[dy][c]  *wv;
            a1 += v[dy+1][c]*wv;
          }
        acc0[o]=a0; acc1[o]=a1;
      }
    }
  }

  const int pix0 = (y0 + 2*r)*WID + x;
  const int pix1 = pix0 + WID;
#pragma unroll
  for (int o=0;o<10;o++){
    const size_t idx = (size_t)(base_nb+o)*HW;
    float u0 = wu[idx+pix0], u1 = wu[idx+pix1];
    float h0 = pb[o*HW+pix0], h1 = pb[o*HW+pix1];
    out[idx+pix0] = (1.f-u0)*h0 + u0*tanh_(acc0[o]);
    out[idx+pix1] = (1.f-u1)*h1 + u1*tanh_(acc1[o]);
  }
}

// ---------------------------------------------------------------------------
extern "C" void kernel_launch(void* const* d_in, const int* in_sizes, int n_in,
                              void* d_out, int out_size, void* d_ws, size_t ws_size,
                              hipStream_t stream)
{
  (void)in_sizes; (void)n_in; (void)out_size; (void)ws_size;
  const float* hn   = (const float*)d_in[1];
  const float* pnn  = (const float*)d_in[2];
  const float* xp   = (const float*)d_in[3];
  const float* Wdau = (const float*)d_in[4];
  const float* bdau = (const float*)d_in[5];
  const float* Wdal = (const float*)d_in[6];
  const float* bdal = (const float*)d_in[7];
  const float* Wd1  = (const float*)d_in[8];
  const float* s1v  = (const float*)d_in[9];
  const float* t1v  = (const float*)d_in[10];
  const float* Wd2  = (const float*)d_in[11];
  const float* s2v  = (const float*)d_in[12];
  const float* t2v  = (const float*)d_in[13];
  const float* Wa0  = (const float*)d_in[14];
  const float* Wa1  = (const float*)d_in[15];
  const float* Wa2  = (const float*)d_in[16];
  const float* Wa3  = (const float*)d_in[17];
  const float* Wa4  = (const float*)d_in[18];
  const float* Wa5  = (const float*)d_in[19];
  const float* batt = (const float*)d_in[20];
  const float* Wp   = (const float*)d_in[21];
  const float* ps   = (const float*)d_in[22];
  const float* pt   = (const float*)d_in[23];
  const float* Wg   = (const float*)d_in[24];
  const float* bg   = (const float*)d_in[25];
  const float* Wc   = (const float*)d_in[26];
  const float* bc   = (const float*)d_in[27];

  float* out = (float*)d_out;
  float* wsf = (float*)d_ws;
  float* ws_msg = wsf;               // [6*4*10*HW] floats
  float* ws_rh  = wsf + 3932160;
  float* ws_u   = wsf + 7864320;

  k_att_dec<<<dim3(1536), dim3(256), 0, stream>>>(hn, pnn, Wdau, bdau, Wdal, bdal,
      Wd1, s1v, t1v, Wd2, s2v, t2v, Wa0, Wa1, Wa2, Wa3, Wa4, Wa5, batt, out, ws_msg);
  k_proj<<<dim3(256), dim3(512), 0, stream>>>(xp, Wp, ps, pt, (const float*)d_out, ws_msg);
  k_gru_gates<<<dim3(768), dim3(256), 0, stream>>>(pnn, Wg, bg, ws_msg, ws_rh, ws_u);
  k_gru_out<<<dim3(768), dim3(256), 0, stream>>>(pnn, Wc, bc, ws_msg, ws_rh, ws_u, out);
}

// Round 5
// 159.252 us; speedup vs baseline: 2.3144x; 1.1662x over previous
//
#include <hip/hip_runtime.h>
#include <math.h>

#define HW    16384
#define WID   128
#define NB    4
// output section offsets (floats)
#define OFF_U 3932160
#define OFF_L 4259840
#define OFF_F 4456448

// conv LDS tile geometry: 4 rows x 136 cols per channel, 10 channels
#define LROW 136
#define LCH  544      // 4*136
#define LDSN 5440     // 10*LCH floats = 21760 B -> 7 blocks/CU (LDS), 6 by grid

typedef __attribute__((ext_vector_type(8))) short  short8_t;
typedef __attribute__((ext_vector_type(4))) float  float4_t;

__device__ __forceinline__ float sig_(float x)  { return 1.f/(1.f+__expf(-x)); }
__device__ __forceinline__ float tanh_(float x) { float e=__expf(2.f*x); return 1.f - 2.f/(e+1.f); }
__device__ __forceinline__ unsigned short f2bf(float x){          // RNE fp32->bf16
  unsigned u = __float_as_uint(x);
  return (unsigned short)((u + 0x7fffu + ((u>>16)&1u)) >> 16);
}

// ---------------------------------------------------------------------------
// Kernel A: node-split (grid 1536 = 6 nodes x 256 pixel-blocks)
// ---------------------------------------------------------------------------
__global__ __launch_bounds__(256)
void k_att_dec(const float* __restrict__ hn, const float* __restrict__ pnn,
               const float* __restrict__ Wdau, const float* __restrict__ bdau,
               const float* __restrict__ Wdal, const float* __restrict__ bdal,
               const float* __restrict__ Wd1, const float* __restrict__ s1v, const float* __restrict__ t1v,
               const float* __restrict__ Wd2, const float* __restrict__ s2v, const float* __restrict__ t2v,
               const float* __restrict__ Wa0, const float* __restrict__ Wa1, const float* __restrict__ Wa2,
               const float* __restrict__ Wa3, const float* __restrict__ Wa4, const float* __restrict__ Wa5,
               const float* __restrict__ batt,
               float* __restrict__ out, float* __restrict__ wmsg)
{
  const int n   = blockIdx.x >> 8;               // node 0..5 (block-uniform)
  const int g   = (blockIdx.x & 255)*256 + threadIdx.x;
  const int b   = g >> 14;
  const int pix = g & 16383;

  float h[10];
  float a;
  if (n < 4){
#pragma unroll
    for (int c=0;c<10;c++) h[c] = hn[(b*10+c)*HW + pix];
    float v[5]; float mx = -1e30f;
#pragma unroll
    for (int o=0;o<5;o++){
      float t = bdau[o];
#pragma unroll
      for (int c=0;c<10;c++) t += Wdau[o*10+c]*h[c];
      if (n==0) out[OFF_U + (b*5+o)*HW + pix] = t;
      v[o]=t; mx = fmaxf(mx,t);
    }
    float s=0.f;
#pragma unroll
    for (int o=0;o<5;o++){ v[o]=__expf(v[o]-mx); s+=v[o]; }
    a = v[n+1]/s;
  } else {
#pragma unroll
    for (int c=0;c<10;c++) h[c] = hn[((NB+b)*10+c)*HW + pix];
    float v[3]; float mx = -1e30f;
#pragma unroll
    for (int o=0;o<3;o++){
      float t = bdal[o];
#pragma unroll
      for (int c=0;c<10;c++) t += Wdal[o*10+c]*h[c];
      if (n==4) out[OFF_L + (b*3+o)*HW + pix] = t;
      v[o]=t; mx = fmaxf(mx,t);
    }
    float s=0.f;
#pragma unroll
    for (int o=0;o<3;o++){ v[o]=__expf(v[o]-mx); s+=v[o]; }
    a = v[n-3]/s;
  }

  float child[10];
#pragma unroll
  for (int c=0;c<10;c++) child[c] = pnn[((n*NB+b)*10+c)*HW + pix];

  float af = batt[n];
  if (n==0){
#pragma unroll
    for (int c=0;c<10;c++) af += Wa0[c]*pnn[((1*NB+b)*10+c)*HW+pix];
  } else if (n==1){
#pragma unroll
    for (int c=0;c<10;c++){
      af += Wa1[c]   *pnn[((0*NB+b)*10+c)*HW+pix];
      af += Wa1[10+c]*pnn[((2*NB+b)*10+c)*HW+pix];
      af += Wa1[20+c]*pnn[((3*NB+b)*10+c)*HW+pix];
      af += Wa1[30+c]*pnn[((4*NB+b)*10+c)*HW+pix];
    }
  } else if (n==2){
#pragma unroll
    for (int c=0;c<10;c++) af += Wa2[c]*pnn[((1*NB+b)*10+c)*HW+pix];
  } else if (n==3){
#pragma unroll
    for (int c=0;c<10;c++) af += Wa3[c]*pnn[((1*NB+b)*10+c)*HW+pix];
  } else if (n==4){
#pragma unroll
    for (int c=0;c<10;c++){
      af += Wa4[c]   *pnn[((1*NB+b)*10+c)*HW+pix];
      af += Wa4[10+c]*pnn[((5*NB+b)*10+c)*HW+pix];
    }
  } else {
#pragma unroll
    for (int c=0;c<10;c++) af += Wa5[c]*pnn[((4*NB+b)*10+c)*HW+pix];
  }
  out[OFF_F + (n*NB+b)*HW + pix] = sig_(af);

  float x20[20];
#pragma unroll
  for (int c=0;c<10;c++){ x20[c]=h[c]*a; x20[10+c]=child[c]; }
  float h20[20];
#pragma unroll
  for (int o=0;o<20;o++){
    float acc=0.f;
#pragma unroll
    for (int c=0;c<20;c++) acc += Wd1[o*20+c]*x20[c];
    h20[o] = fmaxf(acc*s1v[o]+t1v[o], 0.f);
  }
#pragma unroll
  for (int o=0;o<10;o++){
    float acc=0.f;
#pragma unroll
    for (int c=0;c<20;c++) acc += Wd2[o*20+c]*h20[c];
    wmsg[((n*NB+b)*10+o)*HW + pix] = fmaxf(acc*s2v[o]+t2v[o], 0.f);
  }
}

// ---------------------------------------------------------------------------
// Kernel B: projection as bf16 MFMA GEMM.  1024 blocks x 256 thr (4 waves),
// 1 pixel-tile of 16 per wave -> 4 blocks/CU (LDS-limited), 16 waves/CU.
// ---------------------------------------------------------------------------
__global__ __launch_bounds__(256, 2)
void k_proj(const float* __restrict__ xp, const float* __restrict__ Wp,
            const float* __restrict__ ps, const float* __restrict__ pt,
            const float* __restrict__ outf, float* __restrict__ wmsg)
{
  __shared__ unsigned short wlds[64*264];
  const int tid = threadIdx.x;

  for (int e = tid; e < 64*256; e += 256){
    int row = e >> 8, c = e & 255;
    float v = (row < 60) ? Wp[row*256 + c] * ps[row] : 0.f;
    wlds[row*264 + c] = f2bf(v);
  }
  __syncthreads();

  const int l  = tid & 63;
  const int w  = tid >> 6;        // wave 0..3
  const int lr = l & 15;          // A row-in-frag / B col (pixel)
  const int lk = l >> 4;          // k-group 0..3

  // A fragments: k = ks*32 + lk*8 + j (same map as B -> any HW k-perm cancels)
  short8_t wa[4][8];
#pragma unroll
  for (int nf=0;nf<4;nf++)
#pragma unroll
    for (int ks=0;ks<8;ks++)
      wa[nf][ks] = *reinterpret_cast<const short8_t*>(&wlds[(nf*16+lr)*264 + ks*32 + lk*8]);

  const int tile = blockIdx.x*4 + w;
  const int P    = tile*16;
  const int b    = P >> 14;
  const int pixb = P & 16383;
  const int px   = pixb + lr;

  float4_t acc[4];
#pragma unroll
  for (int nf=0;nf<4;nf++){ acc[nf][0]=0.f; acc[nf][1]=0.f; acc[nf][2]=0.f; acc[nf][3]=0.f; }

  const float* xb = xp + (size_t)(b*256)*HW + px;
#pragma unroll
  for (int ks=0;ks<8;ks++){
    const int cb = ks*32 + lk*8;
    float v[8];
#pragma unroll
    for (int j=0;j<8;j++) v[j] = xb[(size_t)(cb+j)*HW];
    short8_t bf;
#pragma unroll
    for (int j=0;j<8;j++) bf[j] = (short)f2bf(v[j]);
#pragma unroll
    for (int nf=0;nf<4;nf++)
      acc[nf] = __builtin_amdgcn_mfma_f32_16x16x32_bf16(wa[nf][ks], bf, acc[nf], 0,0,0);
  }

  // epilogue: row = nf*16 + lk*4 + j  (C/D: col=lane&15, row=(lane>>4)*4+reg)
#pragma unroll
  for (int nf=0;nf<4;nf++){
#pragma unroll
    for (int j=0;j<4;j++){
      const int row = nf*16 + lk*4 + j;
      if (row < 60){
        const unsigned nn = (unsigned)row / 10u;
        const int o = row - (int)nn*10;
        float att = outf[OFF_F + (nn*NB+b)*HW + pixb + lr];
        float val = fmaxf((2.f - att)*acc[nf][j] + pt[row], 0.f);
        size_t idx = ((size_t)((nn*NB+b)*10 + o))*HW + pixb + lr;
        wmsg[idx] += val;
      }
    }
  }
}

// ---------------------------------------------------------------------------
// Kernel C: GRU gates conv, LDS-tiled.  Block = (n, b, 2-row tile), 256 thr,
// 1 pixel/thread.  Grid 1536 -> 6 blocks/CU.  No bounds checks in tap loop.
// ---------------------------------------------------------------------------
__global__ __launch_bounds__(256, 6)
void k_gru_gates(const float* __restrict__ pnn, const float* __restrict__ Wg,
                 const float* __restrict__ bg,
                 const float* __restrict__ wmsg, float* __restrict__ wrh,
                 float* __restrict__ wu)
{
  __shared__ float lds[LDSN];
  const int bi = blockIdx.x;
  const int n  = bi >> 8;             // 6
  const int b  = (bi >> 6) & 3;       // 4
  const int y0 = (bi & 63) * 2;       // 64 tiles of 2 rows
  const int tid = threadIdx.x;
  const int x  = tid & 127;
  const int r  = tid >> 7;            // 0/1

  const int base_nb = (n*NB+b)*10;
  const float* msgb = wmsg + (size_t)base_nb*HW;
  const float* pb   = pnn  + (size_t)base_nb*HW;
  const float* W    = Wg + n*3600;

  float acc[20];
#pragma unroll
  for (int o=0;o<20;o++) acc[o]=bg[n*20+o];

  for (int half=0; half<2; ++half){
    const float* src = (half==0)? msgb : pb;
    __syncthreads();
    for (int e = tid; e < 1280; e += 256){   // 10ch x 4rows x 32 float4
      const int ch  = e >> 7;
      const int rem = e & 127;
      const int r4  = rem >> 5;
      const int q   = rem & 31;
      const int yy  = y0 - 1 + r4;
      float4 v = make_float4(0.f,0.f,0.f,0.f);
      if ((unsigned)yy < 128u)
        v = *reinterpret_cast<const float4*>(src + (size_t)ch*HW + yy*WID + q*4);
      *reinterpret_cast<float4*>(&lds[ch*LCH + r4*LROW + 4 + q*4]) = v;
    }
    if (tid < 80){
      const int ch = tid/8, k2 = tid%8, rr = k2>>1, side = k2&1;
      lds[ch*LCH + rr*LROW + 3 + side*129] = 0.f;   // cols 3 and 132
    }
    __syncthreads();

    for (int ch=0; ch<10; ++ch){
      float v[3][3];
#pragma unroll
      for (int rr=0;rr<3;rr++)
#pragma unroll
        for (int c=0;c<3;c++)
          v[rr][c] = lds[ch*LCH + (r+rr)*LROW + x+3+c];
      const float* Wc0 = W + (half*10+ch)*9;
#pragma unroll
      for (int o=0;o<20;o++){
        const float* w9 = Wc0 + o*180;
        float a0=acc[o];
#pragma unroll
        for (int dy=0;dy<3;dy++)
#pragma unroll
          for (int c=0;c<3;c++)
            a0 += v[dy][c]*w9[dy*3+c];
        acc[o]=a0;
      }
    }
  }

  const int pix = (y0 + r)*WID + x;
#pragma unroll
  for (int o=0;o<10;o++){
    const size_t idx = (size_t)(base_nb+o)*HW;
    float rr = sig_(acc[o]);
    float uu = sig_(acc[10+o]);
    wrh[idx+pix] = rr * pb[o*HW+pix];
    wu [idx+pix] = uu;
  }
}

// ---------------------------------------------------------------------------
// Kernel D: candidate conv + GRU blend, same 2-row tiling
// ---------------------------------------------------------------------------
__global__ __launch_bounds__(256, 6)
void k_gru_out(const float* __restrict__ pnn, const float* __restrict__ Wc,
               const float* __restrict__ bc,
               const float* __restrict__ wmsg, const float* __restrict__ wrh,
               const float* __restrict__ wu, float* __restrict__ out)
{
  __shared__ float lds[LDSN];
  const int bi = blockIdx.x;
  const int n  = bi >> 8;
  const int b  = (bi >> 6) & 3;
  const int y0 = (bi & 63) * 2;
  const int tid = threadIdx.x;
  const int x  = tid & 127;
  const int r  = tid >> 7;

  const int base_nb = (n*NB+b)*10;
  const float* msgb = wmsg + (size_t)base_nb*HW;
  const float* rhb  = wrh  + (size_t)base_nb*HW;
  const float* pb   = pnn  + (size_t)base_nb*HW;
  const float* W    = Wc + n*1800;

  float acc[10];
#pragma unroll
  for (int o=0;o<10;o++) acc[o]=bc[n*10+o];

  for (int half=0; half<2; ++half){
    const float* src = (half==0)? msgb : rhb;
    __syncthreads();
    for (int e = tid; e < 1280; e += 256){
      const int ch  = e >> 7;
      const int rem = e & 127;
      const int r4  = rem >> 5;
      const int q   = rem & 31;
      const int yy  = y0 - 1 + r4;
      float4 v = make_float4(0.f,0.f,0.f,0.f);
      if ((unsigned)yy < 128u)
        v = *reinterpret_cast<const float4*>(src + (size_t)ch*HW + yy*WID + q*4);
      *reinterpret_cast<float4*>(&lds[ch*LCH + r4*LROW + 4 + q*4]) = v;
    }
    if (tid < 80){
      const int ch = tid/8, k2 = tid%8, rr = k2>>1, side = k2&1;
      lds[ch*LCH + rr*LROW + 3 + side*129] = 0.f;
    }
    __syncthreads();

    for (int ch=0; ch<10; ++ch){
      float v[3][3];
#pragma unroll
      for (int rr=0;rr<3;rr++)
#pragma unroll
        for (int c=0;c<3;c++)
          v[rr][c] = lds[ch*LCH + (r+rr)*LROW + x+3+c];
      const float* Wc0 = W + (half*10+ch)*9;
#pragma unroll
      for (int o=0;o<10;o++){
        const float* w9 = Wc0 + o*180;
        float a0=acc[o];
#pragma unroll
        for (int dy=0;dy<3;dy++)
#pragma unroll
          for (int c=0;c<3;c++)
            a0 += v[dy][c]*w9[dy*3+c];
        acc[o]=a0;
      }
    }
  }

  const int pix = (y0 + r)*WID + x;
#pragma unroll
  for (int o=0;o<10;o++){
    const size_t idx = (size_t)(base_nb+o)*HW;
    float uu = wu[idx+pix];
    float hh = pb[o*HW+pix];
    out[idx+pix] = (1.f-uu)*hh + uu*tanh_(acc[o]);
  }
}

// ---------------------------------------------------------------------------
extern "C" void kernel_launch(void* const* d_in, const int* in_sizes, int n_in,
                              void* d_out, int out_size, void* d_ws, size_t ws_size,
                              hipStream_t stream)
{
  (void)in_sizes; (void)n_in; (void)out_size; (void)ws_size;
  const float* hn   = (const float*)d_in[1];
  const float* pnn  = (const float*)d_in[2];
  const float* xp   = (const float*)d_in[3];
  const float* Wdau = (const float*)d_in[4];
  const float* bdau = (const float*)d_in[5];
  const float* Wdal = (const float*)d_in[6];
  const float* bdal = (const float*)d_in[7];
  const float* Wd1  = (const float*)d_in[8];
  const float* s1v  = (const float*)d_in[9];
  const float* t1v  = (const float*)d_in[10];
  const float* Wd2  = (const float*)d_in[11];
  const float* s2v  = (const float*)d_in[12];
  const float* t2v  = (const float*)d_in[13];
  const float* Wa0  = (const float*)d_in[14];
  const float* Wa1  = (const float*)d_in[15];
  const float* Wa2  = (const float*)d_in[16];
  const float* Wa3  = (const float*)d_in[17];
  const float* Wa4  = (const float*)d_in[18];
  const float* Wa5  = (const float*)d_in[19];
  const float* batt = (const float*)d_in[20];
  const float* Wp   = (const float*)d_in[21];
  const float* ps   = (const float*)d_in[22];
  const float* pt   = (const float*)d_in[23];
  const float* Wg   = (const float*)d_in[24];
  const float* bg   = (const float*)d_in[25];
  const float* Wc   = (const float*)d_in[26];
  const float* bc   = (const float*)d_in[27];

  float* out = (float*)d_out;
  float* wsf = (float*)d_ws;
  float* ws_msg = wsf;               // [6*4*10*HW] floats
  float* ws_rh  = wsf + 3932160;
  float* ws_u   = wsf + 7864320;

  k_att_dec<<<dim3(1536), dim3(256), 0, stream>>>(hn, pnn, Wdau, bdau, Wdal, bdal,
      Wd1, s1v, t1v, Wd2, s2v, t2v, Wa0, Wa1, Wa2, Wa3, Wa4, Wa5, batt, out, ws_msg);
  k_proj<<<dim3(1024), dim3(256), 0, stream>>>(xp, Wp, ps, pt, (const float*)d_out, ws_msg);
  k_gru_gates<<<dim3(1536), dim3(256), 0, stream>>>(pnn, Wg, bg, ws_msg, ws_rh, ws_u);
  k_gru_out<<<dim3(1536), dim3(256), 0, stream>>>(pnn, Wc, bc, ws_msg, ws_rh, ws_u, out);
}

// Round 7
// 138.226 us; speedup vs baseline: 2.6665x; 1.1521x over previous
//
#include <hip/hip_runtime.h>
#include <math.h>

#define HW    16384
#define WID   128
#define NB    4
// output section offsets (floats)
#define OFF_U 3932160
#define OFF_L 4259840
#define OFF_F 4456448

// conv tile geometry (ch-interleaved bf16): [4 rows][132 x][24 ch]
#define TCH   24
#define TROW  132
#define TILE_ELEMS (4*TROW*TCH)   // 12672 shorts = 25.3 KB
#define WG_ELEMS   (9*32*TCH)     // 6912 shorts  = 13.8 KB (gates A, o padded to 32)
#define WC_ELEMS   (9*16*TCH)     // 3456 shorts  =  6.9 KB (cand  A, o padded to 16)

typedef __attribute__((ext_vector_type(8))) short  short8_t;
typedef __attribute__((ext_vector_type(4))) float  float4_t;

__device__ __forceinline__ float sig_(float x)  { return 1.f/(1.f+__expf(-x)); }
__device__ __forceinline__ float tanh_(float x) { float e=__expf(2.f*x); return 1.f - 2.f/(e+1.f); }
__device__ __forceinline__ unsigned short f2bf(float x){          // RNE fp32->bf16
  unsigned u = __float_as_uint(x);
  return (unsigned short)((u + 0x7fffu + ((u>>16)&1u)) >> 16);
}

// ---------------------------------------------------------------------------
// Kernel A: node-split (grid 1536 = 6 nodes x 256 pixel-blocks)  [unchanged]
// ---------------------------------------------------------------------------
__global__ __launch_bounds__(256)
void k_att_dec(const float* __restrict__ hn, const float* __restrict__ pnn,
               const float* __restrict__ Wdau, const float* __restrict__ bdau,
               const float* __restrict__ Wdal, const float* __restrict__ bdal,
               const float* __restrict__ Wd1, const float* __restrict__ s1v, const float* __restrict__ t1v,
               const float* __restrict__ Wd2, const float* __restrict__ s2v, const float* __restrict__ t2v,
               const float* __restrict__ Wa0, const float* __restrict__ Wa1, const float* __restrict__ Wa2,
               const float* __restrict__ Wa3, const float* __restrict__ Wa4, const float* __restrict__ Wa5,
               const float* __restrict__ batt,
               float* __restrict__ out, float* __restrict__ wmsg)
{
  const int n   = blockIdx.x >> 8;
  const int g   = (blockIdx.x & 255)*256 + threadIdx.x;
  const int b   = g >> 14;
  const int pix = g & 16383;

  float h[10];
  float a;
  if (n < 4){
#pragma unroll
    for (int c=0;c<10;c++) h[c] = hn[(b*10+c)*HW + pix];
    float v[5]; float mx = -1e30f;
#pragma unroll
    for (int o=0;o<5;o++){
      float t = bdau[o];
#pragma unroll
      for (int c=0;c<10;c++) t += Wdau[o*10+c]*h[c];
      if (n==0) out[OFF_U + (b*5+o)*HW + pix] = t;
      v[o]=t; mx = fmaxf(mx,t);
    }
    float s=0.f;
#pragma unroll
    for (int o=0;o<5;o++){ v[o]=__expf(v[o]-mx); s+=v[o]; }
    a = v[n+1]/s;
  } else {
#pragma unroll
    for (int c=0;c<10;c++) h[c] = hn[((NB+b)*10+c)*HW + pix];
    float v[3]; float mx = -1e30f;
#pragma unroll
    for (int o=0;o<3;o++){
      float t = bdal[o];
#pragma unroll
      for (int c=0;c<10;c++) t += Wdal[o*10+c]*h[c];
      if (n==4) out[OFF_L + (b*3+o)*HW + pix] = t;
      v[o]=t; mx = fmaxf(mx,t);
    }
    float s=0.f;
#pragma unroll
    for (int o=0;o<3;o++){ v[o]=__expf(v[o]-mx); s+=v[o]; }
    a = v[n-3]/s;
  }

  float child[10];
#pragma unroll
  for (int c=0;c<10;c++) child[c] = pnn[((n*NB+b)*10+c)*HW + pix];

  float af = batt[n];
  if (n==0){
#pragma unroll
    for (int c=0;c<10;c++) af += Wa0[c]*pnn[((1*NB+b)*10+c)*HW+pix];
  } else if (n==1){
#pragma unroll
    for (int c=0;c<10;c++){
      af += Wa1[c]   *pnn[((0*NB+b)*10+c)*HW+pix];
      af += Wa1[10+c]*pnn[((2*NB+b)*10+c)*HW+pix];
      af += Wa1[20+c]*pnn[((3*NB+b)*10+c)*HW+pix];
      af += Wa1[30+c]*pnn[((4*NB+b)*10+c)*HW+pix];
    }
  } else if (n==2){
#pragma unroll
    for (int c=0;c<10;c++) af += Wa2[c]*pnn[((1*NB+b)*10+c)*HW+pix];
  } else if (n==3){
#pragma unroll
    for (int c=0;c<10;c++) af += Wa3[c]*pnn[((1*NB+b)*10+c)*HW+pix];
  } else if (n==4){
#pragma unroll
    for (int c=0;c<10;c++){
      af += Wa4[c]   *pnn[((1*NB+b)*10+c)*HW+pix];
      af += Wa4[10+c]*pnn[((5*NB+b)*10+c)*HW+pix];
    }
  } else {
#pragma unroll
    for (int c=0;c<10;c++) af += Wa5[c]*pnn[((4*NB+b)*10+c)*HW+pix];
  }
  out[OFF_F + (n*NB+b)*HW + pix] = sig_(af);

  float x20[20];
#pragma unroll
  for (int c=0;c<10;c++){ x20[c]=h[c]*a; x20[10+c]=child[c]; }
  float h20[20];
#pragma unroll
  for (int o=0;o<20;o++){
    float acc=0.f;
#pragma unroll
    for (int c=0;c<20;c++) acc += Wd1[o*20+c]*x20[c];
    h20[o] = fmaxf(acc*s1v[o]+t1v[o], 0.f);
  }
#pragma unroll
  for (int o=0;o<10;o++){
    float acc=0.f;
#pragma unroll
    for (int c=0;c<20;c++) acc += Wd2[o*20+c]*h20[c];
    wmsg[((n*NB+b)*10+o)*HW + pix] = fmaxf(acc*s2v[o]+t2v[o], 0.f);
  }
}

// ---------------------------------------------------------------------------
// Kernel B: projection as bf16 MFMA GEMM (unchanged)
// ---------------------------------------------------------------------------
__global__ __launch_bounds__(256, 2)
void k_proj(const float* __restrict__ xp, const float* __restrict__ Wp,
            const float* __restrict__ ps, const float* __restrict__ pt,
            const float* __restrict__ outf, float* __restrict__ wmsg)
{
  __shared__ unsigned short wlds[64*264];
  const int tid = threadIdx.x;

  for (int e = tid; e < 64*256; e += 256){
    int row = e >> 8, c = e & 255;
    float v = (row < 60) ? Wp[row*256 + c] * ps[row] : 0.f;
    wlds[row*264 + c] = f2bf(v);
  }
  __syncthreads();

  const int l  = tid & 63;
  const int w  = tid >> 6;
  const int lr = l & 15;
  const int lk = l >> 4;

  short8_t wa[4][8];
#pragma unroll
  for (int nf=0;nf<4;nf++)
#pragma unroll
    for (int ks=0;ks<8;ks++)
      wa[nf][ks] = *reinterpret_cast<const short8_t*>(&wlds[(nf*16+lr)*264 + ks*32 + lk*8]);

  const int tile = blockIdx.x*4 + w;
  const int P    = tile*16;
  const int b    = P >> 14;
  const int pixb = P & 16383;
  const int px   = pixb + lr;

  float4_t acc[4];
#pragma unroll
  for (int nf=0;nf<4;nf++){ acc[nf][0]=0.f; acc[nf][1]=0.f; acc[nf][2]=0.f; acc[nf][3]=0.f; }

  const float* xb = xp + (size_t)(b*256)*HW + px;
#pragma unroll
  for (int ks=0;ks<8;ks++){
    const int cb = ks*32 + lk*8;
    float v[8];
#pragma unroll
    for (int j=0;j<8;j++) v[j] = xb[(size_t)(cb+j)*HW];
    short8_t bf;
#pragma unroll
    for (int j=0;j<8;j++) bf[j] = (short)f2bf(v[j]);
#pragma unroll
    for (int nf=0;nf<4;nf++)
      acc[nf] = __builtin_amdgcn_mfma_f32_16x16x32_bf16(wa[nf][ks], bf, acc[nf], 0,0,0);
  }

#pragma unroll
  for (int nf=0;nf<4;nf++){
#pragma unroll
    for (int j=0;j<4;j++){
      const int row = nf*16 + lk*4 + j;
      if (row < 60){
        const unsigned nn = (unsigned)row / 10u;
        const int o = row - (int)nn*10;
        float att = outf[OFF_F + (nn*NB+b)*HW + pixb + lr];
        float val = fmaxf((2.f - att)*acc[nf][j] + pt[row], 0.f);
        size_t idx = ((size_t)((nn*NB+b)*10 + o))*HW + pixb + lr;
        wmsg[idx] += val;
      }
    }
  }
}

// ---------------------------------------------------------------------------
// Kernel C: GRU gates conv as MFMA implicit-GEMM (9-shift decomposition).
// Tile LDS [4][132][24ch] bf16; A = Wg reorg [9][32][24] bf16.
// Staging decode: e = row*1280 + chp*128 + x   (FIXED from round 6)
// ---------------------------------------------------------------------------
__global__ __launch_bounds__(256, 4)
void k_gru_gates(const float* __restrict__ pnn, const float* __restrict__ Wg,
                 const float* __restrict__ bg,
                 const float* __restrict__ wmsg, float* __restrict__ wrh,
                 float* __restrict__ wu)
{
  __shared__ __align__(16) unsigned short tl[TILE_ELEMS];
  __shared__ __align__(16) unsigned short wl[WG_ELEMS];
  const int bi = blockIdx.x;
  const int n  = bi >> 8;
  const int b  = (bi >> 6) & 3;
  const int y0 = (bi & 63) * 2;
  const int tid = threadIdx.x;

  const int base_nb = (n*NB+b)*10;
  const float* msgb = wmsg + (size_t)base_nb*HW;
  const float* pb   = pnn  + (size_t)base_nb*HW;

  short8_t zz = {0,0,0,0,0,0,0,0};
  for (int e=tid*8; e<TILE_ELEMS; e+=2048) *reinterpret_cast<short8_t*>(&tl[e]) = zz;
  for (int e=tid*8; e<WG_ELEMS;   e+=2048) *reinterpret_cast<short8_t*>(&wl[e]) = zz;
  __syncthreads();

  // weights: Wg[n] is [20 o][20 ch][3][3] -> wl[sh][o][ch] bf16 (ch pairs)
  const float* Wn = Wg + n*3600;
  for (int e=tid; e<1800; e+=256){
    int sh = e/200, rem = e - sh*200, o = rem/10, chp = rem - o*10;
    float w0 = Wn[o*180 + (2*chp  )*9 + sh];
    float w1 = Wn[o*180 + (2*chp+1)*9 + sh];
    unsigned pk = (unsigned)f2bf(w0) | ((unsigned)f2bf(w1)<<16);
    *reinterpret_cast<unsigned*>(&wl[(sh*32+o)*TCH + 2*chp]) = pk;
  }
  // input tile: 4 rows x 10 chp x 128 x  (e = row*1280 + chp*128 + x)
  for (int e=tid; e<5120; e+=256){
    int row = e/1280, rem = e - row*1280, chp = rem>>7, x = rem&127;
    int yy = y0 - 1 + row;
    if ((unsigned)yy < 128u){
      const float* s0 = (chp<5) ? (msgb + (size_t)(2*chp)*HW) : (pb + (size_t)(2*chp-10)*HW);
      float v0 = s0[yy*WID + x];
      float v1 = s0[HW + yy*WID + x];
      unsigned pk = (unsigned)f2bf(v0) | ((unsigned)f2bf(v1)<<16);
      *reinterpret_cast<unsigned*>(&tl[(row*TROW + x+1)*TCH + 2*chp]) = pk;
    }
  }
  __syncthreads();

  const int l  = tid & 63;
  const int w  = tid >> 6;
  const int lr = l & 15;          // frag row (= out ch o) / B col (= pixel)
  const int lk = l >> 4;          // k-group (ch group)

  short8_t wa0[9], wa1[9];
#pragma unroll
  for (int sh=0; sh<9; sh++){
    wa0[sh] = (lk<3) ? *reinterpret_cast<const short8_t*>(&wl[(sh*32 +      lr)*TCH + lk*8]) : zz;
    wa1[sh] = (lk<3) ? *reinterpret_cast<const short8_t*>(&wl[(sh*32 + 16 + lr)*TCH + lk*8]) : zz;
  }
  float bs0[4], bs1[4];
#pragma unroll
  for (int j=0;j<4;j++){
    int o = lk*4 + j;
    bs0[j] = bg[n*20 + o];
    int o1 = 16 + lk*4 + j;
    bs1[j] = (o1 < 20) ? bg[n*20 + o1] : 0.f;
  }

  for (int t=0; t<4; ++t){
    const int tile  = w*4 + t;
    const int row_t = tile >> 3;          // 0/1
    const int xloc  = (tile & 7) * 16;

    float4_t a0 = {0.f,0.f,0.f,0.f}, a1 = {0.f,0.f,0.f,0.f};
#pragma unroll
    for (int sh=0; sh<9; sh++){
      const int dy = sh/3, dx = sh - dy*3;
      const int addr = ((row_t + dy)*TROW + (xloc + lr + dx))*TCH + lk*8;
      short8_t bf = (lk<3) ? *reinterpret_cast<const short8_t*>(&tl[addr]) : zz;
      a0 = __builtin_amdgcn_mfma_f32_16x16x32_bf16(wa0[sh], bf, a0, 0,0,0);
      a1 = __builtin_amdgcn_mfma_f32_16x16x32_bf16(wa1[sh], bf, a1, 0,0,0);
    }

    const int pix = (y0 + row_t)*WID + xloc + lr;
#pragma unroll
    for (int j=0;j<4;j++){
      const int o = lk*4 + j;             // 0..15
      float g = sig_(a0[j] + bs0[j]);
      if (o < 10) wrh[(size_t)(base_nb+o)*HW + pix] = g * pb[(size_t)o*HW + pix];
      else        wu [(size_t)(base_nb+o-10)*HW + pix] = g;
      const int o1 = 16 + lk*4 + j;       // 16..31
      if (o1 < 20){
        float g1 = sig_(a1[j] + bs1[j]);
        wu[(size_t)(base_nb+o1-10)*HW + pix] = g1;
      }
    }
  }
}

// ---------------------------------------------------------------------------
// Kernel D: candidate conv + GRU blend, same MFMA structure (1 out-frag)
// ---------------------------------------------------------------------------
__global__ __launch_bounds__(256, 4)
void k_gru_out(const float* __restrict__ pnn, const float* __restrict__ Wc,
               const float* __restrict__ bc,
               const float* __restrict__ wmsg, const float* __restrict__ wrh,
               const float* __restrict__ wu, float* __restrict__ out)
{
  __shared__ __align__(16) unsigned short tl[TILE_ELEMS];
  __shared__ __align__(16) unsigned short wl[WC_ELEMS];
  const int bi = blockIdx.x;
  const int n  = bi >> 8;
  const int b  = (bi >> 6) & 3;
  const int y0 = (bi & 63) * 2;
  const int tid = threadIdx.x;

  const int base_nb = (n*NB+b)*10;
  const float* msgb = wmsg + (size_t)base_nb*HW;
  const float* rhb  = wrh  + (size_t)base_nb*HW;
  const float* pb   = pnn  + (size_t)base_nb*HW;

  short8_t zz = {0,0,0,0,0,0,0,0};
  for (int e=tid*8; e<TILE_ELEMS; e+=2048) *reinterpret_cast<short8_t*>(&tl[e]) = zz;
  for (int e=tid*8; e<WC_ELEMS;   e+=2048) *reinterpret_cast<short8_t*>(&wl[e]) = zz;
  __syncthreads();

  // weights: Wc[n] is [10 o][20 ch][3][3] -> wl[sh][o(16)][ch] bf16
  const float* Wn = Wc + n*1800;
  for (int e=tid; e<900; e+=256){
    int sh = e/100, rem = e - sh*100, o = rem/10, chp = rem - o*10;
    float w0 = Wn[o*180 + (2*chp  )*9 + sh];
    float w1 = Wn[o*180 + (2*chp+1)*9 + sh];
    unsigned pk = (unsigned)f2bf(w0) | ((unsigned)f2bf(w1)<<16);
    *reinterpret_cast<unsigned*>(&wl[(sh*16+o)*TCH + 2*chp]) = pk;
  }
  // input tile: 4 rows x 10 chp x 128 x  (e = row*1280 + chp*128 + x)
  for (int e=tid; e<5120; e+=256){
    int row = e/1280, rem = e - row*1280, chp = rem>>7, x = rem&127;
    int yy = y0 - 1 + row;
    if ((unsigned)yy < 128u){
      const float* s0 = (chp<5) ? (msgb + (size_t)(2*chp)*HW) : (rhb + (size_t)(2*chp-10)*HW);
      float v0 = s0[yy*WID + x];
      float v1 = s0[HW + yy*WID + x];
      unsigned pk = (unsigned)f2bf(v0) | ((unsigned)f2bf(v1)<<16);
      *reinterpret_cast<unsigned*>(&tl[(row*TROW + x+1)*TCH + 2*chp]) = pk;
    }
  }
  __syncthreads();

  const int l  = tid & 63;
  const int w  = tid >> 6;
  const int lr = l & 15;
  const int lk = l >> 4;

  short8_t wa[9];
#pragma unroll
  for (int sh=0; sh<9; sh++)
    wa[sh] = (lk<3) ? *reinterpret_cast<const short8_t*>(&wl[(sh*16 + lr)*TCH + lk*8]) : zz;

  float bs[4];
#pragma unroll
  for (int j=0;j<4;j++){
    int o = lk*4 + j;
    bs[j] = (o < 10) ? bc[n*10 + o] : 0.f;
  }

  for (int t=0; t<4; ++t){
    const int tile  = w*4 + t;
    const int row_t = tile >> 3;
    const int xloc  = (tile & 7) * 16;

    float4_t a0 = {0.f,0.f,0.f,0.f};
#pragma unroll
    for (int sh=0; sh<9; sh++){
      const int dy = sh/3, dx = sh - dy*3;
      const int addr = ((row_t + dy)*TROW + (xloc + lr + dx))*TCH + lk*8;
      short8_t bf = (lk<3) ? *reinterpret_cast<const short8_t*>(&tl[addr]) : zz;
      a0 = __builtin_amdgcn_mfma_f32_16x16x32_bf16(wa[sh], bf, a0, 0,0,0);
    }

    const int pix = (y0 + row_t)*WID + xloc + lr;
#pragma unroll
    for (int j=0;j<4;j++){
      const int o = lk*4 + j;
      if (o < 10){
        float cand = tanh_(a0[j] + bs[j]);
        float uu = wu[(size_t)(base_nb+o)*HW + pix];
        float hh = pb[(size_t)o*HW + pix];
        out[(size_t)(base_nb+o)*HW + pix] = (1.f-uu)*hh + uu*cand;
      }
    }
  }
}

// ---------------------------------------------------------------------------
extern "C" void kernel_launch(void* const* d_in, const int* in_sizes, int n_in,
                              void* d_out, int out_size, void* d_ws, size_t ws_size,
                              hipStream_t stream)
{
  (void)in_sizes; (void)n_in; (void)out_size; (void)ws_size;
  const float* hn   = (const float*)d_in[1];
  const float* pnn  = (const float*)d_in[2];
  const float* xp   = (const float*)d_in[3];
  const float* Wdau = (const float*)d_in[4];
  const float* bdau = (const float*)d_in[5];
  const float* Wdal = (const float*)d_in[6];
  const float* bdal = (const float*)d_in[7];
  const float* Wd1  = (const float*)d_in[8];
  const float* s1v  = (const float*)d_in[9];
  const float* t1v  = (const float*)d_in[10];
  const float* Wd2  = (const float*)d_in[11];
  const float* s2v  = (const float*)d_in[12];
  const float* t2v  = (const float*)d_in[13];
  const float* Wa0  = (const float*)d_in[14];
  const float* Wa1  = (const float*)d_in[15];
  const float* Wa2  = (const float*)d_in[16];
  const float* Wa3  = (const float*)d_in[17];
  const float* Wa4  = (const float*)d_in[18];
  const float* Wa5  = (const float*)d_in[19];
  const float* batt = (const float*)d_in[20];
  const float* Wp   = (const float*)d_in[21];
  const float* ps   = (const float*)d_in[22];
  const float* pt   = (const float*)d_in[23];
  const float* Wg   = (const float*)d_in[24];
  const float* bg   = (const float*)d_in[25];
  const float* Wc   = (const float*)d_in[26];
  const float* bc   = (const float*)d_in[27];

  float* out = (float*)d_out;
  float* wsf = (float*)d_ws;
  float* ws_msg = wsf;               // [6*4*10*HW] floats
  float* ws_rh  = wsf + 3932160;
  float* ws_u   = wsf + 7864320;

  k_att_dec<<<dim3(1536), dim3(256), 0, stream>>>(hn, pnn, Wdau, bdau, Wdal, bdal,
      Wd1, s1v, t1v, Wd2, s2v, t2v, Wa0, Wa1, Wa2, Wa3, Wa4, Wa5, batt, out, ws_msg);
  k_proj<<<dim3(1024), dim3(256), 0, stream>>>(xp, Wp, ps, pt, (const float*)d_out, ws_msg);
  k_gru_gates<<<dim3(1536), dim3(256), 0, stream>>>(pnn, Wg, bg, ws_msg, ws_rh, ws_u);
  k_gru_out<<<dim3(1536), dim3(256), 0, stream>>>(pnn, Wc, bc, ws_msg, ws_rh, ws_u, out);
}

// Round 8
// 134.508 us; speedup vs baseline: 2.7402x; 1.0276x over previous
//
#include <hip/hip_runtime.h>
#include <math.h>

#define HW    16384
#define WID   128
#define NB    4
// output section offsets (floats)
#define OFF_U 3932160
#define OFF_L 4259840
#define OFF_F 4456448

// conv tile geometry (ch-interleaved bf16): [4 rows][132 x][24 ch]
#define TCH   24
#define TROW  132
#define TILE_ELEMS (4*TROW*TCH)   // 12672 shorts = 25.3 KB
#define WG_ELEMS   (9*32*TCH)     // 6912 shorts  = 13.8 KB (gates A, o padded to 32)
#define WC_ELEMS   (9*16*TCH)     // 3456 shorts  =  6.9 KB (cand  A, o padded to 16)

typedef __attribute__((ext_vector_type(8))) short  short8_t;
typedef __attribute__((ext_vector_type(4))) float  float4_t;

__device__ __forceinline__ float sig_(float x)  { return 1.f/(1.f+__expf(-x)); }
__device__ __forceinline__ float tanh_(float x) { float e=__expf(2.f*x); return 1.f - 2.f/(e+1.f); }
__device__ __forceinline__ unsigned short f2bf(float x){          // RNE fp32->bf16
  unsigned u = __float_as_uint(x);
  return (unsigned short)((u + 0x7fffu + ((u>>16)&1u)) >> 16);
}

// ---------------------------------------------------------------------------
// Kernel A: node-split (grid 1536 = 6 nodes x 256 pixel-blocks)  [unchanged]
// ---------------------------------------------------------------------------
__global__ __launch_bounds__(256)
void k_att_dec(const float* __restrict__ hn, const float* __restrict__ pnn,
               const float* __restrict__ Wdau, const float* __restrict__ bdau,
               const float* __restrict__ Wdal, const float* __restrict__ bdal,
               const float* __restrict__ Wd1, const float* __restrict__ s1v, const float* __restrict__ t1v,
               const float* __restrict__ Wd2, const float* __restrict__ s2v, const float* __restrict__ t2v,
               const float* __restrict__ Wa0, const float* __restrict__ Wa1, const float* __restrict__ Wa2,
               const float* __restrict__ Wa3, const float* __restrict__ Wa4, const float* __restrict__ Wa5,
               const float* __restrict__ batt,
               float* __restrict__ out, float* __restrict__ wmsg)
{
  const int n   = blockIdx.x >> 8;
  const int g   = (blockIdx.x & 255)*256 + threadIdx.x;
  const int b   = g >> 14;
  const int pix = g & 16383;

  float h[10];
  float a;
  if (n < 4){
#pragma unroll
    for (int c=0;c<10;c++) h[c] = hn[(b*10+c)*HW + pix];
    float v[5]; float mx = -1e30f;
#pragma unroll
    for (int o=0;o<5;o++){
      float t = bdau[o];
#pragma unroll
      for (int c=0;c<10;c++) t += Wdau[o*10+c]*h[c];
      if (n==0) out[OFF_U + (b*5+o)*HW + pix] = t;
      v[o]=t; mx = fmaxf(mx,t);
    }
    float s=0.f;
#pragma unroll
    for (int o=0;o<5;o++){ v[o]=__expf(v[o]-mx); s+=v[o]; }
    a = v[n+1]/s;
  } else {
#pragma unroll
    for (int c=0;c<10;c++) h[c] = hn[((NB+b)*10+c)*HW + pix];
    float v[3]; float mx = -1e30f;
#pragma unroll
    for (int o=0;o<3;o++){
      float t = bdal[o];
#pragma unroll
      for (int c=0;c<10;c++) t += Wdal[o*10+c]*h[c];
      if (n==4) out[OFF_L + (b*3+o)*HW + pix] = t;
      v[o]=t; mx = fmaxf(mx,t);
    }
    float s=0.f;
#pragma unroll
    for (int o=0;o<3;o++){ v[o]=__expf(v[o]-mx); s+=v[o]; }
    a = v[n-3]/s;
  }

  float child[10];
#pragma unroll
  for (int c=0;c<10;c++) child[c] = pnn[((n*NB+b)*10+c)*HW + pix];

  float af = batt[n];
  if (n==0){
#pragma unroll
    for (int c=0;c<10;c++) af += Wa0[c]*pnn[((1*NB+b)*10+c)*HW+pix];
  } else if (n==1){
#pragma unroll
    for (int c=0;c<10;c++){
      af += Wa1[c]   *pnn[((0*NB+b)*10+c)*HW+pix];
      af += Wa1[10+c]*pnn[((2*NB+b)*10+c)*HW+pix];
      af += Wa1[20+c]*pnn[((3*NB+b)*10+c)*HW+pix];
      af += Wa1[30+c]*pnn[((4*NB+b)*10+c)*HW+pix];
    }
  } else if (n==2){
#pragma unroll
    for (int c=0;c<10;c++) af += Wa2[c]*pnn[((1*NB+b)*10+c)*HW+pix];
  } else if (n==3){
#pragma unroll
    for (int c=0;c<10;c++) af += Wa3[c]*pnn[((1*NB+b)*10+c)*HW+pix];
  } else if (n==4){
#pragma unroll
    for (int c=0;c<10;c++){
      af += Wa4[c]   *pnn[((1*NB+b)*10+c)*HW+pix];
      af += Wa4[10+c]*pnn[((5*NB+b)*10+c)*HW+pix];
    }
  } else {
#pragma unroll
    for (int c=0;c<10;c++) af += Wa5[c]*pnn[((4*NB+b)*10+c)*HW+pix];
  }
  out[OFF_F + (n*NB+b)*HW + pix] = sig_(af);

  float x20[20];
#pragma unroll
  for (int c=0;c<10;c++){ x20[c]=h[c]*a; x20[10+c]=child[c]; }
  float h20[20];
#pragma unroll
  for (int o=0;o<20;o++){
    float acc=0.f;
#pragma unroll
    for (int c=0;c<20;c++) acc += Wd1[o*20+c]*x20[c];
    h20[o] = fmaxf(acc*s1v[o]+t1v[o], 0.f);
  }
#pragma unroll
  for (int o=0;o<10;o++){
    float acc=0.f;
#pragma unroll
    for (int c=0;c<20;c++) acc += Wd2[o*20+c]*h20[c];
    wmsg[((n*NB+b)*10+o)*HW + pix] = fmaxf(acc*s2v[o]+t2v[o], 0.f);
  }
}

// ---------------------------------------------------------------------------
// Kernel B: projection GEMM, v2.  Block = 64 px, 256 thr (4 waves).
// Stage 1: ps-folded bf16 weights -> wlds[64][264] (float4 loads, uint2 stores)
// Stage 2: xp tile TRANSPOSED -> xt[64 px][264 ch] bf16 (coalesced float4 over
//          pixels; 4 scattered b16 LDS writes/load).  Inner loop pure LDS:
//          8 B-frag + 32 A-frag ds_read_b128 + 32 MFMA.  LDS 67.6KB -> 2 blk/CU.
// ---------------------------------------------------------------------------
__global__ __launch_bounds__(256)
void k_proj(const float* __restrict__ xp, const float* __restrict__ Wp,
            const float* __restrict__ ps, const float* __restrict__ pt,
            const float* __restrict__ outf, float* __restrict__ wmsg)
{
  __shared__ __align__(16) unsigned short wlds[64*264];
  __shared__ __align__(16) unsigned short xt  [64*264];
  const int tid  = threadIdx.x;
  const int P    = blockIdx.x * 64;
  const int b    = P >> 14;
  const int pixb = P & 16383;
  const float* xb0 = xp + (size_t)(b*256)*HW + pixb;

  // ---- stage folded weights (rows 60..63 zero) ----
  for (int e = tid; e < 4096; e += 256){
    const int row = e >> 6, q = e & 63;
    uint2 pk; pk.x = 0u; pk.y = 0u;
    if (row < 60){
      const float s = ps[row];
      float4 wv = *reinterpret_cast<const float4*>(Wp + row*256 + q*4);
      pk.x = (unsigned)f2bf(wv.x*s) | ((unsigned)f2bf(wv.y*s)<<16);
      pk.y = (unsigned)f2bf(wv.z*s) | ((unsigned)f2bf(wv.w*s)<<16);
    }
    *reinterpret_cast<uint2*>(&wlds[row*264 + q*4]) = pk;
  }
  // ---- stage xp tile transposed: [px][ch] ----
  for (int e = tid; e < 4096; e += 256){
    const int ch = e >> 4, q = e & 15;
    float4 v = *reinterpret_cast<const float4*>(xb0 + (size_t)ch*HW + q*4);
    xt[(q*4+0)*264 + ch] = f2bf(v.x);
    xt[(q*4+1)*264 + ch] = f2bf(v.y);
    xt[(q*4+2)*264 + ch] = f2bf(v.z);
    xt[(q*4+3)*264 + ch] = f2bf(v.w);
  }
  __syncthreads();

  const int l  = tid & 63;
  const int w  = tid >> 6;        // wave -> px sub-tile
  const int lr = l & 15;
  const int lk = l >> 4;

  float4_t acc[4];
#pragma unroll
  for (int nf=0;nf<4;nf++){ acc[nf][0]=0.f; acc[nf][1]=0.f; acc[nf][2]=0.f; acc[nf][3]=0.f; }

  const int xrow = (w*16 + lr)*264;
#pragma unroll
  for (int ks=0; ks<8; ks++){
    short8_t bfr = *reinterpret_cast<const short8_t*>(&xt[xrow + ks*32 + lk*8]);
#pragma unroll
    for (int nf=0; nf<4; nf++){
      short8_t wa = *reinterpret_cast<const short8_t*>(&wlds[(nf*16+lr)*264 + ks*32 + lk*8]);
      acc[nf] = __builtin_amdgcn_mfma_f32_16x16x32_bf16(wa, bfr, acc[nf], 0,0,0);
    }
  }

  // epilogue: row = nf*16 + lk*4 + j  (C/D: col=lane&15, row=(lane>>4)*4+reg)
  const int pxo = pixb + w*16 + lr;
#pragma unroll
  for (int nf=0;nf<4;nf++){
#pragma unroll
    for (int j=0;j<4;j++){
      const int row = nf*16 + lk*4 + j;
      if (row < 60){
        const unsigned nn = (unsigned)row / 10u;
        const int o = row - (int)nn*10;
        float att = outf[OFF_F + (nn*NB+b)*HW + pxo];
        float val = fmaxf((2.f - att)*acc[nf][j] + pt[row], 0.f);
        size_t idx = ((size_t)((nn*NB+b)*10 + o))*HW + pxo;
        wmsg[idx] += val;
      }
    }
  }
}

// ---------------------------------------------------------------------------
// Kernel C: GRU gates conv as MFMA implicit-GEMM (unchanged from round 7)
// ---------------------------------------------------------------------------
__global__ __launch_bounds__(256, 4)
void k_gru_gates(const float* __restrict__ pnn, const float* __restrict__ Wg,
                 const float* __restrict__ bg,
                 const float* __restrict__ wmsg, float* __restrict__ wrh,
                 float* __restrict__ wu)
{
  __shared__ __align__(16) unsigned short tl[TILE_ELEMS];
  __shared__ __align__(16) unsigned short wl[WG_ELEMS];
  const int bi = blockIdx.x;
  const int n  = bi >> 8;
  const int b  = (bi >> 6) & 3;
  const int y0 = (bi & 63) * 2;
  const int tid = threadIdx.x;

  const int base_nb = (n*NB+b)*10;
  const float* msgb = wmsg + (size_t)base_nb*HW;
  const float* pb   = pnn  + (size_t)base_nb*HW;

  short8_t zz = {0,0,0,0,0,0,0,0};
  for (int e=tid*8; e<TILE_ELEMS; e+=2048) *reinterpret_cast<short8_t*>(&tl[e]) = zz;
  for (int e=tid*8; e<WG_ELEMS;   e+=2048) *reinterpret_cast<short8_t*>(&wl[e]) = zz;
  __syncthreads();

  const float* Wn = Wg + n*3600;
  for (int e=tid; e<1800; e+=256){
    int sh = e/200, rem = e - sh*200, o = rem/10, chp = rem - o*10;
    float w0 = Wn[o*180 + (2*chp  )*9 + sh];
    float w1 = Wn[o*180 + (2*chp+1)*9 + sh];
    unsigned pk = (unsigned)f2bf(w0) | ((unsigned)f2bf(w1)<<16);
    *reinterpret_cast<unsigned*>(&wl[(sh*32+o)*TCH + 2*chp]) = pk;
  }
  for (int e=tid; e<5120; e+=256){
    int row = e/1280, rem = e - row*1280, chp = rem>>7, x = rem&127;
    int yy = y0 - 1 + row;
    if ((unsigned)yy < 128u){
      const float* s0 = (chp<5) ? (msgb + (size_t)(2*chp)*HW) : (pb + (size_t)(2*chp-10)*HW);
      float v0 = s0[yy*WID + x];
      float v1 = s0[HW + yy*WID + x];
      unsigned pk = (unsigned)f2bf(v0) | ((unsigned)f2bf(v1)<<16);
      *reinterpret_cast<unsigned*>(&tl[(row*TROW + x+1)*TCH + 2*chp]) = pk;
    }
  }
  __syncthreads();

  const int l  = tid & 63;
  const int w  = tid >> 6;
  const int lr = l & 15;
  const int lk = l >> 4;

  short8_t wa0[9], wa1[9];
#pragma unroll
  for (int sh=0; sh<9; sh++){
    wa0[sh] = (lk<3) ? *reinterpret_cast<const short8_t*>(&wl[(sh*32 +      lr)*TCH + lk*8]) : zz;
    wa1[sh] = (lk<3) ? *reinterpret_cast<const short8_t*>(&wl[(sh*32 + 16 + lr)*TCH + lk*8]) : zz;
  }
  float bs0[4], bs1[4];
#pragma unroll
  for (int j=0;j<4;j++){
    int o = lk*4 + j;
    bs0[j] = bg[n*20 + o];
    int o1 = 16 + lk*4 + j;
    bs1[j] = (o1 < 20) ? bg[n*20 + o1] : 0.f;
  }

  for (int t=0; t<4; ++t){
    const int tile  = w*4 + t;
    const int row_t = tile >> 3;
    const int xloc  = (tile & 7) * 16;

    float4_t a0 = {0.f,0.f,0.f,0.f}, a1 = {0.f,0.f,0.f,0.f};
#pragma unroll
    for (int sh=0; sh<9; sh++){
      const int dy = sh/3, dx = sh - dy*3;
      const int addr = ((row_t + dy)*TROW + (xloc + lr + dx))*TCH + lk*8;
      short8_t bf = (lk<3) ? *reinterpret_cast<const short8_t*>(&tl[addr]) : zz;
      a0 = __builtin_amdgcn_mfma_f32_16x16x32_bf16(wa0[sh], bf, a0, 0,0,0);
      a1 = __builtin_amdgcn_mfma_f32_16x16x32_bf16(wa1[sh], bf, a1, 0,0,0);
    }

    const int pix = (y0 + row_t)*WID + xloc + lr;
#pragma unroll
    for (int j=0;j<4;j++){
      const int o = lk*4 + j;
      float g = sig_(a0[j] + bs0[j]);
      if (o < 10) wrh[(size_t)(base_nb+o)*HW + pix] = g * pb[(size_t)o*HW + pix];
      else        wu [(size_t)(base_nb+o-10)*HW + pix] = g;
      const int o1 = 16 + lk*4 + j;
      if (o1 < 20){
        float g1 = sig_(a1[j] + bs1[j]);
        wu[(size_t)(base_nb+o1-10)*HW + pix] = g1;
      }
    }
  }
}

// ---------------------------------------------------------------------------
// Kernel D: candidate conv + GRU blend (unchanged from round 7)
// ---------------------------------------------------------------------------
__global__ __launch_bounds__(256, 4)
void k_gru_out(const float* __restrict__ pnn, const float* __restrict__ Wc,
               const float* __restrict__ bc,
               const float* __restrict__ wmsg, const float* __restrict__ wrh,
               const float* __restrict__ wu, float* __restrict__ out)
{
  __shared__ __align__(16) unsigned short tl[TILE_ELEMS];
  __shared__ __align__(16) unsigned short wl[WC_ELEMS];
  const int bi = blockIdx.x;
  const int n  = bi >> 8;
  const int b  = (bi >> 6) & 3;
  const int y0 = (bi & 63) * 2;
  const int tid = threadIdx.x;

  const int base_nb = (n*NB+b)*10;
  const float* msgb = wmsg + (size_t)base_nb*HW;
  const float* rhb  = wrh  + (size_t)base_nb*HW;
  const float* pb   = pnn  + (size_t)base_nb*HW;

  short8_t zz = {0,0,0,0,0,0,0,0};
  for (int e=tid*8; e<TILE_ELEMS; e+=2048) *reinterpret_cast<short8_t*>(&tl[e]) = zz;
  for (int e=tid*8; e<WC_ELEMS;   e+=2048) *reinterpret_cast<short8_t*>(&wl[e]) = zz;
  __syncthreads();

  const float* Wn = Wc + n*1800;
  for (int e=tid; e<900; e+=256){
    int sh = e/100, rem = e - sh*100, o = rem/10, chp = rem - o*10;
    float w0 = Wn[o*180 + (2*chp  )*9 + sh];
    float w1 = Wn[o*180 + (2*chp+1)*9 + sh];
    unsigned pk = (unsigned)f2bf(w0) | ((unsigned)f2bf(w1)<<16);
    *reinterpret_cast<unsigned*>(&wl[(sh*16+o)*TCH + 2*chp]) = pk;
  }
  for (int e=tid; e<5120; e+=256){
    int row = e/1280, rem = e - row*1280, chp = rem>>7, x = rem&127;
    int yy = y0 - 1 + row;
    if ((unsigned)yy < 128u){
      const float* s0 = (chp<5) ? (msgb + (size_t)(2*chp)*HW) : (rhb + (size_t)(2*chp-10)*HW);
      float v0 = s0[yy*WID + x];
      float v1 = s0[HW + yy*WID + x];
      unsigned pk = (unsigned)f2bf(v0) | ((unsigned)f2bf(v1)<<16);
      *reinterpret_cast<unsigned*>(&tl[(row*TROW + x+1)*TCH + 2*chp]) = pk;
    }
  }
  __syncthreads();

  const int l  = tid & 63;
  const int w  = tid >> 6;
  const int lr = l & 15;
  const int lk = l >> 4;

  short8_t wa[9];
#pragma unroll
  for (int sh=0; sh<9; sh++)
    wa[sh] = (lk<3) ? *reinterpret_cast<const short8_t*>(&wl[(sh*16 + lr)*TCH + lk*8]) : zz;

  float bs[4];
#pragma unroll
  for (int j=0;j<4;j++){
    int o = lk*4 + j;
    bs[j] = (o < 10) ? bc[n*10 + o] : 0.f;
  }

  for (int t=0; t<4; ++t){
    const int tile  = w*4 + t;
    const int row_t = tile >> 3;
    const int xloc  = (tile & 7) * 16;

    float4_t a0 = {0.f,0.f,0.f,0.f};
#pragma unroll
    for (int sh=0; sh<9; sh++){
      const int dy = sh/3, dx = sh - dy*3;
      const int addr = ((row_t + dy)*TROW + (xloc + lr + dx))*TCH + lk*8;
      short8_t bf = (lk<3) ? *reinterpret_cast<const short8_t*>(&tl[addr]) : zz;
      a0 = __builtin_amdgcn_mfma_f32_16x16x32_bf16(wa[sh], bf, a0, 0,0,0);
    }

    const int pix = (y0 + row_t)*WID + xloc + lr;
#pragma unroll
    for (int j=0;j<4;j++){
      const int o = lk*4 + j;
      if (o < 10){
        float cand = tanh_(a0[j] + bs[j]);
        float uu = wu[(size_t)(base_nb+o)*HW + pix];
        float hh = pb[(size_t)o*HW + pix];
        out[(size_t)(base_nb+o)*HW + pix] = (1.f-uu)*hh + uu*cand;
      }
    }
  }
}

// ---------------------------------------------------------------------------
extern "C" void kernel_launch(void* const* d_in, const int* in_sizes, int n_in,
                              void* d_out, int out_size, void* d_ws, size_t ws_size,
                              hipStream_t stream)
{
  (void)in_sizes; (void)n_in; (void)out_size; (void)ws_size;
  const float* hn   = (const float*)d_in[1];
  const float* pnn  = (const float*)d_in[2];
  const float* xp   = (const float*)d_in[3];
  const float* Wdau = (const float*)d_in[4];
  const float* bdau = (const float*)d_in[5];
  const float* Wdal = (const float*)d_in[6];
  const float* bdal = (const float*)d_in[7];
  const float* Wd1  = (const float*)d_in[8];
  const float* s1v  = (const float*)d_in[9];
  const float* t1v  = (const float*)d_in[10];
  const float* Wd2  = (const float*)d_in[11];
  const float* s2v  = (const float*)d_in[12];
  const float* t2v  = (const float*)d_in[13];
  const float* Wa0  = (const float*)d_in[14];
  const float* Wa1  = (const float*)d_in[15];
  const float* Wa2  = (const float*)d_in[16];
  const float* Wa3  = (const float*)d_in[17];
  const float* Wa4  = (const float*)d_in[18];
  const float* Wa5  = (const float*)d_in[19];
  const float* batt = (const float*)d_in[20];
  const float* Wp   = (const float*)d_in[21];
  const float* ps   = (const float*)d_in[22];
  const float* pt   = (const float*)d_in[23];
  const float* Wg   = (const float*)d_in[24];
  const float* bg   = (const float*)d_in[25];
  const float* Wc   = (const float*)d_in[26];
  const float* bc   = (const float*)d_in[27];

  float* out = (float*)d_out;
  float* wsf = (float*)d_ws;
  float* ws_msg = wsf;               // [6*4*10*HW] floats
  float* ws_rh  = wsf + 3932160;
  float* ws_u   = wsf + 7864320;

  k_att_dec<<<dim3(1536), dim3(256), 0, stream>>>(hn, pnn, Wdau, bdau, Wdal, bdal,
      Wd1, s1v, t1v, Wd2, s2v, t2v, Wa0, Wa1, Wa2, Wa3, Wa4, Wa5, batt, out, ws_msg);
  k_proj<<<dim3(1024), dim3(256), 0, stream>>>(xp, Wp, ps, pt, (const float*)d_out, ws_msg);
  k_gru_gates<<<dim3(1536), dim3(256), 0, stream>>>(pnn, Wg, bg, ws_msg, ws_rh, ws_u);
  k_gru_out<<<dim3(1536), dim3(256), 0, stream>>>(pnn, Wc, bc, ws_msg, ws_rh, ws_u, out);
}

// Round 9
// 116.863 us; speedup vs baseline: 3.1539x; 1.1510x over previous
//
#include <hip/hip_runtime.h>
#include <math.h>

#define HW    16384
#define WID   128
#define NB    4
// output section offsets (floats)
#define OFF_U 3932160
#define OFF_L 4259840
#define OFF_F 4456448

// conv tile geometry (ch-interleaved bf16): [4 rows][132 x][24 ch]
#define TCH   24
#define TROW  132
#define TILE_ELEMS (4*TROW*TCH)   // 12672 shorts = 25.3 KB
#define WG_ELEMS   (9*32*TCH)     // 6912 shorts  = 13.8 KB
#define WC_ELEMS   (9*16*TCH)     // 3456 shorts  =  6.9 KB

typedef __attribute__((ext_vector_type(8))) short  short8_t;
typedef __attribute__((ext_vector_type(4))) float  float4_t;

__device__ __forceinline__ float sig_(float x)  { return 1.f/(1.f+__expf(-x)); }
__device__ __forceinline__ float tanh_(float x) { float e=__expf(2.f*x); return 1.f - 2.f/(e+1.f); }
__device__ __forceinline__ unsigned short f2bf(float x){          // RNE fp32->bf16
  unsigned u = __float_as_uint(x);
  return (unsigned short)((u + 0x7fffu + ((u>>16)&1u)) >> 16);
}

// ---------------------------------------------------------------------------
// Kernel A: node-split (grid 1536 = 6 nodes x 256 pixel-blocks)  [unchanged]
// ---------------------------------------------------------------------------
__global__ __launch_bounds__(256)
void k_att_dec(const float* __restrict__ hn, const float* __restrict__ pnn,
               const float* __restrict__ Wdau, const float* __restrict__ bdau,
               const float* __restrict__ Wdal, const float* __restrict__ bdal,
               const float* __restrict__ Wd1, const float* __restrict__ s1v, const float* __restrict__ t1v,
               const float* __restrict__ Wd2, const float* __restrict__ s2v, const float* __restrict__ t2v,
               const float* __restrict__ Wa0, const float* __restrict__ Wa1, const float* __restrict__ Wa2,
               const float* __restrict__ Wa3, const float* __restrict__ Wa4, const float* __restrict__ Wa5,
               const float* __restrict__ batt,
               float* __restrict__ out, float* __restrict__ wmsg)
{
  const int n   = blockIdx.x >> 8;
  const int g   = (blockIdx.x & 255)*256 + threadIdx.x;
  const int b   = g >> 14;
  const int pix = g & 16383;

  float h[10];
  float a;
  if (n < 4){
#pragma unroll
    for (int c=0;c<10;c++) h[c] = hn[(b*10+c)*HW + pix];
    float v[5]; float mx = -1e30f;
#pragma unroll
    for (int o=0;o<5;o++){
      float t = bdau[o];
#pragma unroll
      for (int c=0;c<10;c++) t += Wdau[o*10+c]*h[c];
      if (n==0) out[OFF_U + (b*5+o)*HW + pix] = t;
      v[o]=t; mx = fmaxf(mx,t);
    }
    float s=0.f;
#pragma unroll
    for (int o=0;o<5;o++){ v[o]=__expf(v[o]-mx); s+=v[o]; }
    a = v[n+1]/s;
  } else {
#pragma unroll
    for (int c=0;c<10;c++) h[c] = hn[((NB+b)*10+c)*HW + pix];
    float v[3]; float mx = -1e30f;
#pragma unroll
    for (int o=0;o<3;o++){
      float t = bdal[o];
#pragma unroll
      for (int c=0;c<10;c++) t += Wdal[o*10+c]*h[c];
      if (n==4) out[OFF_L + (b*3+o)*HW + pix] = t;
      v[o]=t; mx = fmaxf(mx,t);
    }
    float s=0.f;
#pragma unroll
    for (int o=0;o<3;o++){ v[o]=__expf(v[o]-mx); s+=v[o]; }
    a = v[n-3]/s;
  }

  float child[10];
#pragma unroll
  for (int c=0;c<10;c++) child[c] = pnn[((n*NB+b)*10+c)*HW + pix];

  float af = batt[n];
  if (n==0){
#pragma unroll
    for (int c=0;c<10;c++) af += Wa0[c]*pnn[((1*NB+b)*10+c)*HW+pix];
  } else if (n==1){
#pragma unroll
    for (int c=0;c<10;c++){
      af += Wa1[c]   *pnn[((0*NB+b)*10+c)*HW+pix];
      af += Wa1[10+c]*pnn[((2*NB+b)*10+c)*HW+pix];
      af += Wa1[20+c]*pnn[((3*NB+b)*10+c)*HW+pix];
      af += Wa1[30+c]*pnn[((4*NB+b)*10+c)*HW+pix];
    }
  } else if (n==2){
#pragma unroll
    for (int c=0;c<10;c++) af += Wa2[c]*pnn[((1*NB+b)*10+c)*HW+pix];
  } else if (n==3){
#pragma unroll
    for (int c=0;c<10;c++) af += Wa3[c]*pnn[((1*NB+b)*10+c)*HW+pix];
  } else if (n==4){
#pragma unroll
    for (int c=0;c<10;c++){
      af += Wa4[c]   *pnn[((1*NB+b)*10+c)*HW+pix];
      af += Wa4[10+c]*pnn[((5*NB+b)*10+c)*HW+pix];
    }
  } else {
#pragma unroll
    for (int c=0;c<10;c++) af += Wa5[c]*pnn[((4*NB+b)*10+c)*HW+pix];
  }
  out[OFF_F + (n*NB+b)*HW + pix] = sig_(af);

  float x20[20];
#pragma unroll
  for (int c=0;c<10;c++){ x20[c]=h[c]*a; x20[10+c]=child[c]; }
  float h20[20];
#pragma unroll
  for (int o=0;o<20;o++){
    float acc=0.f;
#pragma unroll
    for (int c=0;c<20;c++) acc += Wd1[o*20+c]*x20[c];
    h20[o] = fmaxf(acc*s1v[o]+t1v[o], 0.f);
  }
#pragma unroll
  for (int o=0;o<10;o++){
    float acc=0.f;
#pragma unroll
    for (int c=0;c<20;c++) acc += Wd2[o*20+c]*h20[c];
    wmsg[((n*NB+b)*10+o)*HW + pix] = fmaxf(acc*s2v[o]+t2v[o], 0.f);
  }
}

// ---------------------------------------------------------------------------
// Kernel B: projection GEMM v3.  1024 blocks x 256 thr (4 waves), 1 tile/wave.
// LDS = weights only (33.8 KB -> 4 blocks/CU, 16 waves/CU).
// xp loads fully unrolled into v[64]: all 64 independent loads in flight.
// ---------------------------------------------------------------------------
__global__ __launch_bounds__(256, 2)
void k_proj(const float* __restrict__ xp, const float* __restrict__ Wp,
            const float* __restrict__ ps, const float* __restrict__ pt,
            const float* __restrict__ outf, float* __restrict__ wmsg)
{
  __shared__ __align__(16) unsigned short wlds[64*264];
  const int tid = threadIdx.x;

  // stage ps-folded weights (rows 60..63 zero); 16 const-trip iterations
#pragma unroll
  for (int it=0; it<16; ++it){
    const int e = tid + it*256;
    const int row = e >> 6, q = e & 63;
    uint2 pk; pk.x = 0u; pk.y = 0u;
    if (row < 60){
      const float s = ps[row];
      float4 wv = *reinterpret_cast<const float4*>(Wp + row*256 + q*4);
      pk.x = (unsigned)f2bf(wv.x*s) | ((unsigned)f2bf(wv.y*s)<<16);
      pk.y = (unsigned)f2bf(wv.z*s) | ((unsigned)f2bf(wv.w*s)<<16);
    }
    *reinterpret_cast<uint2*>(&wlds[row*264 + q*4]) = pk;
  }
  __syncthreads();

  const int l  = tid & 63;
  const int w  = tid >> 6;
  const int lr = l & 15;
  const int lk = l >> 4;

  const int tile = blockIdx.x*4 + w;
  const int P    = tile*16;
  const int b    = P >> 14;
  const int pixb = P & 16383;
  const int px   = pixb + lr;

  // all 64 xp loads issued up-front (independent)
  const float* xb = xp + (size_t)(b*256)*HW + px;
  float v[64];
#pragma unroll
  for (int ks=0; ks<8; ++ks)
#pragma unroll
    for (int j=0; j<8; ++j)
      v[ks*8+j] = xb[(size_t)(ks*32 + lk*8 + j)*HW];

  short8_t bf[8];
#pragma unroll
  for (int ks=0; ks<8; ++ks)
#pragma unroll
    for (int j=0; j<8; ++j)
      bf[ks][j] = (short)f2bf(v[ks*8+j]);

  float4_t acc[4];
#pragma unroll
  for (int nf=0;nf<4;nf++){ acc[nf][0]=0.f; acc[nf][1]=0.f; acc[nf][2]=0.f; acc[nf][3]=0.f; }

#pragma unroll
  for (int ks=0; ks<8; ++ks){
#pragma unroll
    for (int nf=0; nf<4; ++nf){
      short8_t wa = *reinterpret_cast<const short8_t*>(&wlds[(nf*16+lr)*264 + ks*32 + lk*8]);
      acc[nf] = __builtin_amdgcn_mfma_f32_16x16x32_bf16(wa, bf[ks], acc[nf], 0,0,0);
    }
  }

  // epilogue: row = nf*16 + lk*4 + j  (C/D: col=lane&15, row=(lane>>4)*4+reg)
#pragma unroll
  for (int nf=0;nf<4;nf++){
#pragma unroll
    for (int j=0;j<4;j++){
      const int row = nf*16 + lk*4 + j;
      if (row < 60){
        const unsigned nn = (unsigned)row / 10u;
        const int o = row - (int)nn*10;
        float att = outf[OFF_F + (nn*NB+b)*HW + pixb + lr];
        float val = fmaxf((2.f - att)*acc[nf][j] + pt[row], 0.f);
        size_t idx = ((size_t)((nn*NB+b)*10 + o))*HW + pixb + lr;
        wmsg[idx] += val;
      }
    }
  }
}

// ---------------------------------------------------------------------------
// Kernel C: GRU gates conv (MFMA implicit-GEMM).  Staging loops fully
// unrolled with const trip counts so all global loads issue up-front.
// ---------------------------------------------------------------------------
__global__ __launch_bounds__(256, 4)
void k_gru_gates(const float* __restrict__ pnn, const float* __restrict__ Wg,
                 const float* __restrict__ bg,
                 const float* __restrict__ wmsg, float* __restrict__ wrh,
                 float* __restrict__ wu)
{
  __shared__ __align__(16) unsigned short tl[TILE_ELEMS];
  __shared__ __align__(16) unsigned short wl[WG_ELEMS];
  const int bi = blockIdx.x;
  const int n  = bi >> 8;
  const int b  = (bi >> 6) & 3;
  const int y0 = (bi & 63) * 2;
  const int tid = threadIdx.x;

  const int base_nb = (n*NB+b)*10;
  const float* msgb = wmsg + (size_t)base_nb*HW;
  const float* pb   = pnn  + (size_t)base_nb*HW;

  short8_t zz = {0,0,0,0,0,0,0,0};
#pragma unroll
  for (int it=0; it<7; ++it){
    const int e = tid*8 + it*2048;
    if (e < TILE_ELEMS) *reinterpret_cast<short8_t*>(&tl[e]) = zz;
  }
#pragma unroll
  for (int it=0; it<4; ++it){
    const int e = tid*8 + it*2048;
    if (e < WG_ELEMS) *reinterpret_cast<short8_t*>(&wl[e]) = zz;
  }
  __syncthreads();

  const float* Wn = Wg + n*3600;
#pragma unroll
  for (int it=0; it<8; ++it){
    const int e = tid + it*256;
    if (e < 1800){
      int sh = e/200, rem = e - sh*200, o = rem/10, chp = rem - o*10;
      float w0 = Wn[o*180 + (2*chp  )*9 + sh];
      float w1 = Wn[o*180 + (2*chp+1)*9 + sh];
      unsigned pk = (unsigned)f2bf(w0) | ((unsigned)f2bf(w1)<<16);
      *reinterpret_cast<unsigned*>(&wl[(sh*32+o)*TCH + 2*chp]) = pk;
    }
  }
#pragma unroll
  for (int it=0; it<20; ++it){
    const int e = tid + it*256;           // e < 5120 always
    int row = e/1280, rem = e - row*1280, chp = rem>>7, x = rem&127;
    int yy = y0 - 1 + row;
    if ((unsigned)yy < 128u){
      const float* s0 = (chp<5) ? (msgb + (size_t)(2*chp)*HW) : (pb + (size_t)(2*chp-10)*HW);
      float v0 = s0[yy*WID + x];
      float v1 = s0[HW + yy*WID + x];
      unsigned pk = (unsigned)f2bf(v0) | ((unsigned)f2bf(v1)<<16);
      *reinterpret_cast<unsigned*>(&tl[(row*TROW + x+1)*TCH + 2*chp]) = pk;
    }
  }
  __syncthreads();

  const int l  = tid & 63;
  const int w  = tid >> 6;
  const int lr = l & 15;
  const int lk = l >> 4;

  short8_t wa0[9], wa1[9];
#pragma unroll
  for (int sh=0; sh<9; sh++){
    wa0[sh] = (lk<3) ? *reinterpret_cast<const short8_t*>(&wl[(sh*32 +      lr)*TCH + lk*8]) : zz;
    wa1[sh] = (lk<3) ? *reinterpret_cast<const short8_t*>(&wl[(sh*32 + 16 + lr)*TCH + lk*8]) : zz;
  }
  float bs0[4], bs1[4];
#pragma unroll
  for (int j=0;j<4;j++){
    int o = lk*4 + j;
    bs0[j] = bg[n*20 + o];
    int o1 = 16 + lk*4 + j;
    bs1[j] = (o1 < 20) ? bg[n*20 + o1] : 0.f;
  }

  for (int t=0; t<4; ++t){
    const int tile  = w*4 + t;
    const int row_t = tile >> 3;
    const int xloc  = (tile & 7) * 16;

    float4_t a0 = {0.f,0.f,0.f,0.f}, a1 = {0.f,0.f,0.f,0.f};
#pragma unroll
    for (int sh=0; sh<9; sh++){
      const int dy = sh/3, dx = sh - dy*3;
      const int addr = ((row_t + dy)*TROW + (xloc + lr + dx))*TCH + lk*8;
      short8_t bf = (lk<3) ? *reinterpret_cast<const short8_t*>(&tl[addr]) : zz;
      a0 = __builtin_amdgcn_mfma_f32_16x16x32_bf16(wa0[sh], bf, a0, 0,0,0);
      a1 = __builtin_amdgcn_mfma_f32_16x16x32_bf16(wa1[sh], bf, a1, 0,0,0);
    }

    const int pix = (y0 + row_t)*WID + xloc + lr;
#pragma unroll
    for (int j=0;j<4;j++){
      const int o = lk*4 + j;
      float g = sig_(a0[j] + bs0[j]);
      if (o < 10) wrh[(size_t)(base_nb+o)*HW + pix] = g * pb[(size_t)o*HW + pix];
      else        wu [(size_t)(base_nb+o-10)*HW + pix] = g;
      const int o1 = 16 + lk*4 + j;
      if (o1 < 20){
        float g1 = sig_(a1[j] + bs1[j]);
        wu[(size_t)(base_nb+o1-10)*HW + pix] = g1;
      }
    }
  }
}

// ---------------------------------------------------------------------------
// Kernel D: candidate conv + GRU blend, same batched staging
// ---------------------------------------------------------------------------
__global__ __launch_bounds__(256, 4)
void k_gru_out(const float* __restrict__ pnn, const float* __restrict__ Wc,
               const float* __restrict__ bc,
               const float* __restrict__ wmsg, const float* __restrict__ wrh,
               const float* __restrict__ wu, float* __restrict__ out)
{
  __shared__ __align__(16) unsigned short tl[TILE_ELEMS];
  __shared__ __align__(16) unsigned short wl[WC_ELEMS];
  const int bi = blockIdx.x;
  const int n  = bi >> 8;
  const int b  = (bi >> 6) & 3;
  const int y0 = (bi & 63) * 2;
  const int tid = threadIdx.x;

  const int base_nb = (n*NB+b)*10;
  const float* msgb = wmsg + (size_t)base_nb*HW;
  const float* rhb  = wrh  + (size_t)base_nb*HW;
  const float* pb   = pnn  + (size_t)base_nb*HW;

  short8_t zz = {0,0,0,0,0,0,0,0};
#pragma unroll
  for (int it=0; it<7; ++it){
    const int e = tid*8 + it*2048;
    if (e < TILE_ELEMS) *reinterpret_cast<short8_t*>(&tl[e]) = zz;
  }
#pragma unroll
  for (int it=0; it<2; ++it){
    const int e = tid*8 + it*2048;
    if (e < WC_ELEMS) *reinterpret_cast<short8_t*>(&wl[e]) = zz;
  }
  __syncthreads();

  const float* Wn = Wc + n*1800;
#pragma unroll
  for (int it=0; it<4; ++it){
    const int e = tid + it*256;
    if (e < 900){
      int sh = e/100, rem = e - sh*100, o = rem/10, chp = rem - o*10;
      float w0 = Wn[o*180 + (2*chp  )*9 + sh];
      float w1 = Wn[o*180 + (2*chp+1)*9 + sh];
      unsigned pk = (unsigned)f2bf(w0) | ((unsigned)f2bf(w1)<<16);
      *reinterpret_cast<unsigned*>(&wl[(sh*16+o)*TCH + 2*chp]) = pk;
    }
  }
#pragma unroll
  for (int it=0; it<20; ++it){
    const int e = tid + it*256;
    int row = e/1280, rem = e - row*1280, chp = rem>>7, x = rem&127;
    int yy = y0 - 1 + row;
    if ((unsigned)yy < 128u){
      const float* s0 = (chp<5) ? (msgb + (size_t)(2*chp)*HW) : (rhb + (size_t)(2*chp-10)*HW);
      float v0 = s0[yy*WID + x];
      float v1 = s0[HW + yy*WID + x];
      unsigned pk = (unsigned)f2bf(v0) | ((unsigned)f2bf(v1)<<16);
      *reinterpret_cast<unsigned*>(&tl[(row*TROW + x+1)*TCH + 2*chp]) = pk;
    }
  }
  __syncthreads();

  const int l  = tid & 63;
  const int w  = tid >> 6;
  const int lr = l & 15;
  const int lk = l >> 4;

  short8_t wa[9];
#pragma unroll
  for (int sh=0; sh<9; sh++)
    wa[sh] = (lk<3) ? *reinterpret_cast<const short8_t*>(&wl[(sh*16 + lr)*TCH + lk*8]) : zz;

  float bs[4];
#pragma unroll
  for (int j=0;j<4;j++){
    int o = lk*4 + j;
    bs[j] = (o < 10) ? bc[n*10 + o] : 0.f;
  }

  for (int t=0; t<4; ++t){
    const int tile  = w*4 + t;
    const int row_t = tile >> 3;
    const int xloc  = (tile & 7) * 16;

    float4_t a0 = {0.f,0.f,0.f,0.f};
#pragma unroll
    for (int sh=0; sh<9; sh++){
      const int dy = sh/3, dx = sh - dy*3;
      const int addr = ((row_t + dy)*TROW + (xloc + lr + dx))*TCH + lk*8;
      short8_t bf = (lk<3) ? *reinterpret_cast<const short8_t*>(&tl[addr]) : zz;
      a0 = __builtin_amdgcn_mfma_f32_16x16x32_bf16(wa[sh], bf, a0, 0,0,0);
    }

    const int pix = (y0 + row_t)*WID + xloc + lr;
#pragma unroll
    for (int j=0;j<4;j++){
      const int o = lk*4 + j;
      if (o < 10){
        float cand = tanh_(a0[j] + bs[j]);
        float uu = wu[(size_t)(base_nb+o)*HW + pix];
        float hh = pb[(size_t)o*HW + pix];
        out[(size_t)(base_nb+o)*HW + pix] = (1.f-uu)*hh + uu*cand;
      }
    }
  }
}

// ---------------------------------------------------------------------------
extern "C" void kernel_launch(void* const* d_in, const int* in_sizes, int n_in,
                              void* d_out, int out_size, void* d_ws, size_t ws_size,
                              hipStream_t stream)
{
  (void)in_sizes; (void)n_in; (void)out_size; (void)ws_size;
  const float* hn   = (const float*)d_in[1];
  const float* pnn  = (const float*)d_in[2];
  const float* xp   = (const float*)d_in[3];
  const float* Wdau = (const float*)d_in[4];
  const float* bdau = (const float*)d_in[5];
  const float* Wdal = (const float*)d_in[6];
  const float* bdal = (const float*)d_in[7];
  const float* Wd1  = (const float*)d_in[8];
  const float* s1v  = (const float*)d_in[9];
  const float* t1v  = (const float*)d_in[10];
  const float* Wd2  = (const float*)d_in[11];
  const float* s2v  = (const float*)d_in[12];
  const float* t2v  = (const float*)d_in[13];
  const float* Wa0  = (const float*)d_in[14];
  const float* Wa1  = (const float*)d_in[15];
  const float* Wa2  = (const float*)d_in[16];
  const float* Wa3  = (const float*)d_in[17];
  const float* Wa4  = (const float*)d_in[18];
  const float* Wa5  = (const float*)d_in[19];
  const float* batt = (const float*)d_in[20];
  const float* Wp   = (const float*)d_in[21];
  const float* ps   = (const float*)d_in[22];
  const float* pt   = (const float*)d_in[23];
  const float* Wg   = (const float*)d_in[24];
  const float* bg   = (const float*)d_in[25];
  const float* Wc   = (const float*)d_in[26];
  const float* bc   = (const float*)d_in[27];

  float* out = (float*)d_out;
  float* wsf = (float*)d_ws;
  float* ws_msg = wsf;               // [6*4*10*HW] floats
  float* ws_rh  = wsf + 3932160;
  float* ws_u   = wsf + 7864320;

  k_att_dec<<<dim3(1536), dim3(256), 0, stream>>>(hn, pnn, Wdau, bdau, Wdal, bdal,
      Wd1, s1v, t1v, Wd2, s2v, t2v, Wa0, Wa1, Wa2, Wa3, Wa4, Wa5, batt, out, ws_msg);
  k_proj<<<dim3(1024), dim3(256), 0, stream>>>(xp, Wp, ps, pt, (const float*)d_out, ws_msg);
  k_gru_gates<<<dim3(1536), dim3(256), 0, stream>>>(pnn, Wg, bg, ws_msg, ws_rh, ws_u);
  k_gru_out<<<dim3(1536), dim3(256), 0, stream>>>(pnn, Wc, bc, ws_msg, ws_rh, ws_u, out);
}